// Round 1
// baseline (1166.001 us; speedup 1.0000x reference)
//
#include <hip/hip_runtime.h>
#include <hip/hip_bf16.h>
#include <math.h>

#define Nn 20000
#define En 320000
#define Gn 16
#define DINn 1280
#define Hn 256
#define Cn 500
#define EPSn 1e-5f

// ---------------- degree / norm / CSR build ----------------

__global__ void k_deg(const int* col, const float* ew, float* deg) {
    int e = blockIdx.x * blockDim.x + threadIdx.x;
    if (e < En) atomicAdd(&deg[col[e]], ew[e]);
}

__global__ void k_dinv(const float* deg, float* dinv, float* dinv2) {
    int i = blockIdx.x * blockDim.x + threadIdx.x;
    if (i < Nn) {
        float d = deg[i] + 1.0f;
        float r = rsqrtf(d);
        dinv[i] = r;
        dinv2[i] = 1.0f / d;
    }
}

__global__ void k_norm_count(const int* row, const int* col, const float* ew,
                             const float* dinv, float* normE, int* counts) {
    int e = blockIdx.x * blockDim.x + threadIdx.x;
    if (e < En) {
        int r = row[e], c = col[e];
        normE[e] = dinv[r] * ew[e] * dinv[c];
        atomicAdd(&counts[c], 1);
    }
}

// single-block exclusive scan over counts -> offsets, cursor
__global__ void k_scan(const int* counts, int* offsets, int* cursor) {
    __shared__ int sdata[1024];
    __shared__ int s_running;
    int tid = threadIdx.x;
    if (tid == 0) s_running = 0;
    __syncthreads();
    for (int base = 0; base < Nn; base += 1024) {
        int i = base + tid;
        int v = (i < Nn) ? counts[i] : 0;
        sdata[tid] = v;
        __syncthreads();
        #pragma unroll
        for (int offi = 1; offi < 1024; offi <<= 1) {
            int t = (tid >= offi) ? sdata[tid - offi] : 0;
            __syncthreads();
            sdata[tid] += t;
            __syncthreads();
        }
        int incl = sdata[tid];
        int excl = incl - v;
        if (i < Nn) {
            int o = s_running + excl;
            offsets[i] = o;
            cursor[i] = o;
        }
        __syncthreads();
        if (tid == 1023) s_running += sdata[1023];
        __syncthreads();
    }
    if (tid == 0) offsets[Nn] = s_running;
}

__global__ void k_fill(const int* row, const int* col, const float* normE,
                       int* cursor, int* csr_row, float* csr_w) {
    int e = blockIdx.x * blockDim.x + threadIdx.x;
    if (e < En) {
        int c = col[e];
        int p = atomicAdd(&cursor[c], 1);
        csr_row[p] = row[e];
        csr_w[p] = normE[e];
    }
}

// ---------------- GEMM: C[M x 256] = (scale*A+shift) @ W ----------------
// A: M x K row-major, W: K x 256 row-major.

#define BM 64
#define BNt 64
#define BK 16

__global__ __launch_bounds__(256) void k_gemm(const float* __restrict__ A,
                                              const float* __restrict__ W,
                                              float* __restrict__ Cmat,
                                              int M, int K,
                                              const float* __restrict__ scale,
                                              const float* __restrict__ shift) {
    __shared__ float As[BK][BM + 1];
    __shared__ float Ws[BK][BNt];
    int bm = blockIdx.x * BM;
    int bn = blockIdx.y * BNt;
    int tid = threadIdx.x;
    int tx = tid % 16, ty = tid / 16;
    float acc[4][4] = {};

    for (int k0 = 0; k0 < K; k0 += BK) {
        // A tile: rows bm..bm+63, cols k0..k0+15
        int c = tid % 16;
        int r0 = tid / 16;
        #pragma unroll
        for (int rr = 0; rr < 4; rr++) {
            int r = r0 + rr * 16;
            int gr = bm + r;
            float v = 0.0f;
            if (gr < M) {
                v = A[(size_t)gr * K + k0 + c];
                if (scale) v = v * scale[k0 + c] + shift[k0 + c];
            }
            As[c][r] = v;
        }
        // W tile: rows k0..k0+15, cols bn..bn+63
        int wc = tid % 64, wr0 = tid / 64;
        #pragma unroll
        for (int rr = 0; rr < 4; rr++) {
            int wr = wr0 + rr * 4;
            Ws[wr][wc] = W[(size_t)(k0 + wr) * Hn + bn + wc];
        }
        __syncthreads();
        #pragma unroll
        for (int kk = 0; kk < BK; kk++) {
            float a[4], b[4];
            #pragma unroll
            for (int i = 0; i < 4; i++) a[i] = As[kk][ty + i * 16];
            #pragma unroll
            for (int j = 0; j < 4; j++) b[j] = Ws[kk][tx + j * 16];
            #pragma unroll
            for (int i = 0; i < 4; i++)
                #pragma unroll
                for (int j = 0; j < 4; j++)
                    acc[i][j] += a[i] * b[j];
        }
        __syncthreads();
    }
    #pragma unroll
    for (int i = 0; i < 4; i++) {
        int gr = bm + ty + i * 16;
        if (gr < M) {
            #pragma unroll
            for (int j = 0; j < 4; j++)
                Cmat[(size_t)gr * Hn + bn + tx + j * 16] = acc[i][j];
        }
    }
}

// ---------------- aggregation (one node per block) ----------------

__global__ __launch_bounds__(256) void k_agg(const float* __restrict__ xw,
                                             const int* __restrict__ offsets,
                                             const int* __restrict__ csr_row,
                                             const float* __restrict__ csr_w,
                                             const float* __restrict__ dinv2,
                                             const float* __restrict__ bias,
                                             float* __restrict__ outp, int do_relu) {
    int i = blockIdx.x;
    int h = threadIdx.x;
    int s = offsets[i], e = offsets[i + 1];
    float acc = 0.0f;
    for (int k = s; k < e; k++) {
        int r = csr_row[k];
        float w = csr_w[k];
        acc += w * xw[(size_t)r * Hn + h];
    }
    acc += dinv2[i] * xw[(size_t)i * Hn + h];
    acc += bias[h];
    if (do_relu) acc = fmaxf(acc, 0.0f);
    outp[(size_t)i * Hn + h] = acc;
}

// ---------------- batch-norm stats ----------------

__global__ __launch_bounds__(256) void k_bnstats(const float* __restrict__ h, float* __restrict__ stats) {
    int f = threadIdx.x;
    float s = 0.0f, ss = 0.0f;
    for (int i = blockIdx.x; i < Nn; i += gridDim.x) {
        float v = h[(size_t)i * Hn + f];
        s += v;
        ss += v * v;
    }
    atomicAdd(&stats[f], s);
    atomicAdd(&stats[Hn + f], ss);
}

__global__ void k_bnfinal(const float* stats, const float* g, const float* be,
                          float* scaleA, float* shiftA) {
    int f = threadIdx.x;
    float mean = stats[f] / (float)Nn;
    float var = stats[Hn + f] / (float)Nn - mean * mean;
    float a = g[f] * rsqrtf(var + EPSn);
    scaleA[f] = a;
    shiftA[f] = be[f] - mean * a;
}

// ---------------- pooling ----------------

__global__ void k_cnt(const int* batch, float* cnt) {
    int i = blockIdx.x * blockDim.x + threadIdx.x;
    if (i < Nn) atomicAdd(&cnt[batch[i]], 1.0f);
}

__global__ __launch_bounds__(256) void k_pool(const float* __restrict__ h,
                                              const int* __restrict__ batch,
                                              const float* __restrict__ scaleA,
                                              const float* __restrict__ shiftA,
                                              float* __restrict__ pooled) {
    int i = blockIdx.x;
    int f = threadIdx.x;
    float v = h[(size_t)i * Hn + f] * scaleA[f] + shiftA[f];
    atomicAdd(&pooled[batch[i] * Hn + f], v);
}

// ---------------- head: y = seq_emb@fc1_w + fc1_b; pfinal = pooled/cnt + y ----------------

__global__ __launch_bounds__(256) void k_head1(const float* __restrict__ seq_emb,
                                               const float* __restrict__ fc1_w,
                                               const float* __restrict__ fc1_b,
                                               const float* __restrict__ pooled,
                                               const float* __restrict__ cnt,
                                               float* __restrict__ pfinal) {
    int gidx = blockIdx.x;   // 16
    int j = threadIdx.x;     // 256
    float acc = fc1_b[j];
    const float* se = &seq_emb[(size_t)gidx * DINn];
    for (int k = 0; k < DINn; k++)
        acc += se[k] * fc1_w[(size_t)k * Hn + j];
    pfinal[gidx * Hn + j] = pooled[gidx * Hn + j] / fmaxf(cnt[gidx], 1.0f) + acc;
}

__global__ __launch_bounds__(512) void k_head2(const float* __restrict__ pfinal,
                                               const float* __restrict__ lin_w,
                                               const float* __restrict__ lin_b,
                                               float* __restrict__ out) {
    int gidx = blockIdx.x;   // 16
    int c = threadIdx.x;     // 512 (guard 500)
    if (c >= Cn) return;
    float acc = lin_b[c];
    const float* p = &pfinal[gidx * Hn];
    for (int k = 0; k < Hn; k++)
        acc += p[k] * lin_w[(size_t)k * Cn + c];
    out[gidx * Cn + c] = 1.0f / (1.0f + expf(-acc));
}

// ---------------- launch ----------------

extern "C" void kernel_launch(void* const* d_in, const int* in_sizes, int n_in,
                              void* d_out, int out_size, void* d_ws, size_t ws_size,
                              hipStream_t stream) {
    const float* x        = (const float*)d_in[0];
    const int*   eidx     = (const int*)d_in[1];
    const float* eattr    = (const float*)d_in[2];
    const int*   batch    = (const int*)d_in[3];
    const float* seq_emb  = (const float*)d_in[4];
    const float* W1 = (const float*)d_in[5];
    const float* b1 = (const float*)d_in[6];
    const float* g1 = (const float*)d_in[7];
    const float* be1 = (const float*)d_in[8];
    const float* W2 = (const float*)d_in[9];
    const float* b2 = (const float*)d_in[10];
    const float* g2 = (const float*)d_in[11];
    const float* be2 = (const float*)d_in[12];
    const float* W3 = (const float*)d_in[13];
    const float* b3 = (const float*)d_in[14];
    const float* g3 = (const float*)d_in[15];
    const float* be3 = (const float*)d_in[16];
    const float* fc1_w = (const float*)d_in[17];
    const float* fc1_b = (const float*)d_in[18];
    const float* lin_w = (const float*)d_in[19];
    const float* lin_b = (const float*)d_in[20];
    float* out = (float*)d_out;

    const int* row = eidx;
    const int* col = eidx + En;

    // workspace carve-up
    char* ws = (char*)d_ws;
    size_t off = 0;
    auto alloc = [&](size_t bytes) -> char* {
        char* p = ws + off;
        off += (bytes + 255) & ~(size_t)255;
        return p;
    };
    float* xw      = (float*)alloc((size_t)Nn * Hn * 4);
    float* hbuf    = (float*)alloc((size_t)Nn * Hn * 4);
    float* deg     = (float*)alloc(Nn * 4);
    int*   counts  = (int*)alloc(Nn * 4);      // NOTE: deg+counts zeroed separately
    float* dinv    = (float*)alloc(Nn * 4);
    float* dinv2   = (float*)alloc(Nn * 4);
    float* normE   = (float*)alloc(En * 4);
    int*   offsets = (int*)alloc((Nn + 1) * 4);
    int*   cursor  = (int*)alloc(Nn * 4);
    int*   csr_row = (int*)alloc(En * 4);
    float* csr_w   = (float*)alloc(En * 4);
    float* stats   = (float*)alloc(2 * Hn * 4);
    float* scaleA  = (float*)alloc(Hn * 4);
    float* shiftA  = (float*)alloc(Hn * 4);
    float* pooled  = (float*)alloc(Gn * Hn * 4);
    float* cnt     = (float*)alloc(Gn * 4);
    float* pfinal  = (float*)alloc(Gn * Hn * 4);

    const int TB = 256;
    const int EB = (En + TB - 1) / TB;
    const int NB = (Nn + TB - 1) / TB;

    // ---- graph prep ----
    hipMemsetAsync(deg, 0, Nn * 4, stream);
    hipMemsetAsync(counts, 0, Nn * 4, stream);
    k_deg<<<EB, TB, 0, stream>>>(col, eattr, deg);
    k_dinv<<<NB, TB, 0, stream>>>(deg, dinv, dinv2);
    k_norm_count<<<EB, TB, 0, stream>>>(row, col, eattr, dinv, normE, counts);
    k_scan<<<1, 1024, 0, stream>>>(counts, offsets, cursor);
    k_fill<<<EB, TB, 0, stream>>>(row, col, normE, cursor, csr_row, csr_w);

    dim3 gemm_grid1((Nn + BM - 1) / BM, Hn / BNt);

    // ---- layer 1 ----
    k_gemm<<<gemm_grid1, 256, 0, stream>>>(x, W1, xw, Nn, DINn, nullptr, nullptr);
    k_agg<<<Nn, Hn, 0, stream>>>(xw, offsets, csr_row, csr_w, dinv2, b1, hbuf, 1);
    hipMemsetAsync(stats, 0, 2 * Hn * 4, stream);
    k_bnstats<<<256, Hn, 0, stream>>>(hbuf, stats);
    k_bnfinal<<<1, Hn, 0, stream>>>(stats, g1, be1, scaleA, shiftA);

    // ---- layer 2 ----
    k_gemm<<<gemm_grid1, 256, 0, stream>>>(hbuf, W2, xw, Nn, Hn, scaleA, shiftA);
    k_agg<<<Nn, Hn, 0, stream>>>(xw, offsets, csr_row, csr_w, dinv2, b2, hbuf, 1);
    hipMemsetAsync(stats, 0, 2 * Hn * 4, stream);
    k_bnstats<<<256, Hn, 0, stream>>>(hbuf, stats);
    k_bnfinal<<<1, Hn, 0, stream>>>(stats, g2, be2, scaleA, shiftA);

    // ---- layer 3 ----
    k_gemm<<<gemm_grid1, 256, 0, stream>>>(hbuf, W3, xw, Nn, Hn, scaleA, shiftA);
    k_agg<<<Nn, Hn, 0, stream>>>(xw, offsets, csr_row, csr_w, dinv2, b3, hbuf, 0);
    hipMemsetAsync(stats, 0, 2 * Hn * 4, stream);
    k_bnstats<<<256, Hn, 0, stream>>>(hbuf, stats);
    k_bnfinal<<<1, Hn, 0, stream>>>(stats, g3, be3, scaleA, shiftA);

    // ---- pooling ----
    hipMemsetAsync(pooled, 0, Gn * Hn * 4, stream);
    hipMemsetAsync(cnt, 0, Gn * 4, stream);
    k_cnt<<<NB, TB, 0, stream>>>(batch, cnt);
    k_pool<<<Nn, Hn, 0, stream>>>(hbuf, batch, scaleA, shiftA, pooled);

    // ---- head ----
    k_head1<<<Gn, Hn, 0, stream>>>(seq_emb, fc1_w, fc1_b, pooled, cnt, pfinal);
    k_head2<<<Gn, 512, 0, stream>>>(pfinal, lin_w, lin_b, out);
}

// Round 2
// 907.770 us; speedup vs baseline: 1.2845x; 1.2845x over previous
//
#include <hip/hip_runtime.h>
#include <hip/hip_bf16.h>
#include <math.h>

#define Nn 20000
#define En 320000
#define Gn 16
#define DINn 1280
#define Hn 256
#define Cn 500
#define EPSn 1e-5f

typedef __attribute__((ext_vector_type(8))) short bf16x8;
typedef __attribute__((ext_vector_type(4))) float f32x4;

// ---------------- degree / norm / CSR build ----------------

__global__ void k_deg(const int* col, const float* ew, float* deg) {
    int e = blockIdx.x * blockDim.x + threadIdx.x;
    if (e < En) atomicAdd(&deg[col[e]], ew[e]);
}

__global__ void k_dinv(const float* deg, float* dinv, float* dinv2) {
    int i = blockIdx.x * blockDim.x + threadIdx.x;
    if (i < Nn) {
        float d = deg[i] + 1.0f;
        float r = rsqrtf(d);
        dinv[i] = r;
        dinv2[i] = 1.0f / d;
    }
}

__global__ void k_norm_count(const int* row, const int* col, const float* ew,
                             const float* dinv, float* normE, int* counts) {
    int e = blockIdx.x * blockDim.x + threadIdx.x;
    if (e < En) {
        int r = row[e], c = col[e];
        normE[e] = dinv[r] * ew[e] * dinv[c];
        atomicAdd(&counts[c], 1);
    }
}

// single-block exclusive scan over counts -> offsets, cursor
__global__ void k_scan(const int* counts, int* offsets, int* cursor) {
    __shared__ int sdata[1024];
    __shared__ int s_running;
    int tid = threadIdx.x;
    if (tid == 0) s_running = 0;
    __syncthreads();
    for (int base = 0; base < Nn; base += 1024) {
        int i = base + tid;
        int v = (i < Nn) ? counts[i] : 0;
        sdata[tid] = v;
        __syncthreads();
        #pragma unroll
        for (int offi = 1; offi < 1024; offi <<= 1) {
            int t = (tid >= offi) ? sdata[tid - offi] : 0;
            __syncthreads();
            sdata[tid] += t;
            __syncthreads();
        }
        int incl = sdata[tid];
        int excl = incl - v;
        if (i < Nn) {
            int o = s_running + excl;
            offsets[i] = o;
            cursor[i] = o;
        }
        __syncthreads();
        if (tid == 1023) s_running += sdata[1023];
        __syncthreads();
    }
    if (tid == 0) offsets[Nn] = s_running;
}

__global__ void k_fill(const int* row, const int* col, const float* normE,
                       int* cursor, int* csr_row, float* csr_w) {
    int e = blockIdx.x * blockDim.x + threadIdx.x;
    if (e < En) {
        int c = col[e];
        int p = atomicAdd(&cursor[c], 1);
        csr_row[p] = row[e];
        csr_w[p] = normE[e];
    }
}

// ---------------- weight transpose + bf16 convert: WT[n][k] = bf16(W[k][n]) ----------------

__global__ __launch_bounds__(256) void k_wt(const float* __restrict__ W,
                                            ushort* __restrict__ WT, int K) {
    __shared__ float tile[32][33];
    int k0 = blockIdx.x * 32, n0 = blockIdx.y * 32;
    int tx = threadIdx.x, ty = threadIdx.y;   // (32, 8)
    #pragma unroll
    for (int i = 0; i < 32; i += 8)
        tile[ty + i][tx] = W[(size_t)(k0 + ty + i) * Hn + n0 + tx];
    __syncthreads();
    #pragma unroll
    for (int i = 0; i < 32; i += 8) {
        __hip_bfloat16 h = __float2bfloat16(tile[tx][ty + i]);
        WT[(size_t)(n0 + ty + i) * K + k0 + tx] = *reinterpret_cast<ushort*>(&h);
    }
}

// ---------------- MFMA GEMM: C[M x 256] = bf16(scale*A+shift) @ bf16(W) ----------------
// A: M x K f32 row-major. BT: 256 x K bf16 (W transposed). C: M x 256 f32.

#define GBM 128
#define GBK 32

__global__ __launch_bounds__(256) void k_gemm_mfma(
    const float* __restrict__ A, const ushort* __restrict__ BT,
    float* __restrict__ Cmat, int M, int K,
    const float* __restrict__ scale, const float* __restrict__ shift)
{
    __shared__ ushort Asl[128][40];   // padded: stride 80B -> 2-way bank alias (free)
    __shared__ ushort Bsl[128][40];
    const int bm = blockIdx.x * GBM;
    const int bn = blockIdx.y * 128;
    const int tid = threadIdx.x;
    const int lane = tid & 63;
    const int wid = tid >> 6;
    const int wm = wid >> 1, wn = wid & 1;    // 2x2 waves, 64x64 each
    const int l15 = lane & 15, l16 = lane >> 4;

    const int srow = tid >> 1;     // 0..127
    const int shalf = tid & 1;     // k-offset 0/16
    const bool avalid = (bm + srow) < M;

    f32x4 acc[4][4] = {};

    for (int k0 = 0; k0 < K; k0 += GBK) {
        // ---- stage A: 16 f32 -> 16 bf16 per thread (fused BN affine) ----
        ushort tmpa[16];
        if (avalid) {
            const float4* ap = reinterpret_cast<const float4*>(
                &A[(size_t)(bm + srow) * K + k0 + shalf * 16]);
            #pragma unroll
            for (int q = 0; q < 4; q++) {
                float4 f = ap[q];
                if (scale) {
                    const float4 s = reinterpret_cast<const float4*>(&scale[k0 + shalf * 16])[q];
                    const float4 t = reinterpret_cast<const float4*>(&shift[k0 + shalf * 16])[q];
                    f.x = f.x * s.x + t.x; f.y = f.y * s.y + t.y;
                    f.z = f.z * s.z + t.z; f.w = f.w * s.w + t.w;
                }
                __hip_bfloat16 h0 = __float2bfloat16(f.x), h1 = __float2bfloat16(f.y),
                               h2 = __float2bfloat16(f.z), h3 = __float2bfloat16(f.w);
                tmpa[q * 4 + 0] = *reinterpret_cast<ushort*>(&h0);
                tmpa[q * 4 + 1] = *reinterpret_cast<ushort*>(&h1);
                tmpa[q * 4 + 2] = *reinterpret_cast<ushort*>(&h2);
                tmpa[q * 4 + 3] = *reinterpret_cast<ushort*>(&h3);
            }
        } else {
            #pragma unroll
            for (int q = 0; q < 16; q++) tmpa[q] = 0;
        }
        *reinterpret_cast<uint4*>(&Asl[srow][shalf * 16]) = *reinterpret_cast<uint4*>(&tmpa[0]);
        *reinterpret_cast<uint4*>(&Asl[srow][shalf * 16 + 8]) = *reinterpret_cast<uint4*>(&tmpa[8]);

        // ---- stage B: 16 bf16 per thread from BT ----
        const uint4* bp = reinterpret_cast<const uint4*>(
            &BT[(size_t)(bn + srow) * K + k0 + shalf * 16]);
        uint4 b0 = bp[0], b1 = bp[1];
        *reinterpret_cast<uint4*>(&Bsl[srow][shalf * 16]) = b0;
        *reinterpret_cast<uint4*>(&Bsl[srow][shalf * 16 + 8]) = b1;

        __syncthreads();

        // ---- compute: 8 x ds_read_b128 + 16 MFMA per wave ----
        bf16x8 afr[4], bfr[4];
        #pragma unroll
        for (int i = 0; i < 4; i++)
            afr[i] = *reinterpret_cast<const bf16x8*>(&Asl[wm * 64 + i * 16 + l15][l16 * 8]);
        #pragma unroll
        for (int j = 0; j < 4; j++)
            bfr[j] = *reinterpret_cast<const bf16x8*>(&Bsl[wn * 64 + j * 16 + l15][l16 * 8]);
        #pragma unroll
        for (int i = 0; i < 4; i++)
            #pragma unroll
            for (int j = 0; j < 4; j++)
                acc[i][j] = __builtin_amdgcn_mfma_f32_16x16x32_bf16(afr[i], bfr[j], acc[i][j], 0, 0, 0);

        __syncthreads();
    }

    // ---- epilogue: D col = lane&15, row = 4*(lane>>4)+r ----
    #pragma unroll
    for (int i = 0; i < 4; i++) {
        #pragma unroll
        for (int r = 0; r < 4; r++) {
            int grow = bm + wm * 64 + i * 16 + l16 * 4 + r;
            if (grow < M) {
                #pragma unroll
                for (int j = 0; j < 4; j++)
                    Cmat[(size_t)grow * Hn + bn + wn * 64 + j * 16 + l15] = acc[i][j][r];
            }
        }
    }
}

// ---------------- aggregation (one node per block) ----------------

__global__ __launch_bounds__(256) void k_agg(const float* __restrict__ xw,
                                             const int* __restrict__ offsets,
                                             const int* __restrict__ csr_row,
                                             const float* __restrict__ csr_w,
                                             const float* __restrict__ dinv2,
                                             const float* __restrict__ bias,
                                             float* __restrict__ outp, int do_relu) {
    int i = blockIdx.x;
    int h = threadIdx.x;
    int s = offsets[i], e = offsets[i + 1];
    float acc = 0.0f;
    for (int k = s; k < e; k++) {
        int r = csr_row[k];
        float w = csr_w[k];
        acc += w * xw[(size_t)r * Hn + h];
    }
    acc += dinv2[i] * xw[(size_t)i * Hn + h];
    acc += bias[h];
    if (do_relu) acc = fmaxf(acc, 0.0f);
    outp[(size_t)i * Hn + h] = acc;
}

// ---------------- batch-norm stats ----------------

__global__ __launch_bounds__(256) void k_bnstats(const float* __restrict__ h, float* __restrict__ stats) {
    int f = threadIdx.x;
    float s = 0.0f, ss = 0.0f;
    for (int i = blockIdx.x; i < Nn; i += gridDim.x) {
        float v = h[(size_t)i * Hn + f];
        s += v;
        ss += v * v;
    }
    atomicAdd(&stats[f], s);
    atomicAdd(&stats[Hn + f], ss);
}

__global__ void k_bnfinal(const float* stats, const float* g, const float* be,
                          float* scaleA, float* shiftA) {
    int f = threadIdx.x;
    float mean = stats[f] / (float)Nn;
    float var = stats[Hn + f] / (float)Nn - mean * mean;
    float a = g[f] * rsqrtf(var + EPSn);
    scaleA[f] = a;
    shiftA[f] = be[f] - mean * a;
}

// ---------------- pooling ----------------

__global__ void k_cnt(const int* batch, float* cnt) {
    int i = blockIdx.x * blockDim.x + threadIdx.x;
    if (i < Nn) atomicAdd(&cnt[batch[i]], 1.0f);
}

__global__ __launch_bounds__(256) void k_pool(const float* __restrict__ h,
                                              const int* __restrict__ batch,
                                              const float* __restrict__ scaleA,
                                              const float* __restrict__ shiftA,
                                              float* __restrict__ pooled) {
    int i = blockIdx.x;
    int f = threadIdx.x;
    float v = h[(size_t)i * Hn + f] * scaleA[f] + shiftA[f];
    atomicAdd(&pooled[batch[i] * Hn + f], v);
}

// ---------------- head ----------------

__global__ __launch_bounds__(256) void k_head1(const float* __restrict__ seq_emb,
                                               const float* __restrict__ fc1_w,
                                               const float* __restrict__ fc1_b,
                                               const float* __restrict__ pooled,
                                               const float* __restrict__ cnt,
                                               float* __restrict__ pfinal) {
    int gidx = blockIdx.x;   // 16
    int j = threadIdx.x;     // 256
    float acc = fc1_b[j];
    const float* se = &seq_emb[(size_t)gidx * DINn];
    #pragma unroll 8
    for (int k = 0; k < DINn; k++)
        acc += se[k] * fc1_w[(size_t)k * Hn + j];
    pfinal[gidx * Hn + j] = pooled[gidx * Hn + j] / fmaxf(cnt[gidx], 1.0f) + acc;
}

__global__ __launch_bounds__(512) void k_head2(const float* __restrict__ pfinal,
                                               const float* __restrict__ lin_w,
                                               const float* __restrict__ lin_b,
                                               float* __restrict__ out) {
    int gidx = blockIdx.x;   // 16
    int c = threadIdx.x;     // 512 (guard 500)
    if (c >= Cn) return;
    float acc = lin_b[c];
    const float* p = &pfinal[gidx * Hn];
    #pragma unroll 8
    for (int k = 0; k < Hn; k++)
        acc += p[k] * lin_w[(size_t)k * Cn + c];
    out[gidx * Cn + c] = 1.0f / (1.0f + expf(-acc));
}

// ---------------- launch ----------------

extern "C" void kernel_launch(void* const* d_in, const int* in_sizes, int n_in,
                              void* d_out, int out_size, void* d_ws, size_t ws_size,
                              hipStream_t stream) {
    const float* x        = (const float*)d_in[0];
    const int*   eidx     = (const int*)d_in[1];
    const float* eattr    = (const float*)d_in[2];
    const int*   batch    = (const int*)d_in[3];
    const float* seq_emb  = (const float*)d_in[4];
    const float* W1 = (const float*)d_in[5];
    const float* b1 = (const float*)d_in[6];
    const float* g1 = (const float*)d_in[7];
    const float* be1 = (const float*)d_in[8];
    const float* W2 = (const float*)d_in[9];
    const float* b2 = (const float*)d_in[10];
    const float* g2 = (const float*)d_in[11];
    const float* be2 = (const float*)d_in[12];
    const float* W3 = (const float*)d_in[13];
    const float* b3 = (const float*)d_in[14];
    const float* g3 = (const float*)d_in[15];
    const float* be3 = (const float*)d_in[16];
    const float* fc1_w = (const float*)d_in[17];
    const float* fc1_b = (const float*)d_in[18];
    const float* lin_w = (const float*)d_in[19];
    const float* lin_b = (const float*)d_in[20];
    float* out = (float*)d_out;

    const int* row = eidx;
    const int* col = eidx + En;

    // workspace carve-up
    char* ws = (char*)d_ws;
    size_t off = 0;
    auto alloc = [&](size_t bytes) -> char* {
        char* p = ws + off;
        off += (bytes + 255) & ~(size_t)255;
        return p;
    };
    float* xw      = (float*)alloc((size_t)Nn * Hn * 4);
    float* hbuf    = (float*)alloc((size_t)Nn * Hn * 4);
    float* deg     = (float*)alloc(Nn * 4);
    int*   counts  = (int*)alloc(Nn * 4);
    float* dinv    = (float*)alloc(Nn * 4);
    float* dinv2   = (float*)alloc(Nn * 4);
    float* normE   = (float*)alloc(En * 4);
    int*   offsets = (int*)alloc((Nn + 1) * 4);
    int*   cursor  = (int*)alloc(Nn * 4);
    int*   csr_row = (int*)alloc(En * 4);
    float* csr_w   = (float*)alloc(En * 4);
    float* stats   = (float*)alloc(2 * Hn * 4);
    float* scaleA  = (float*)alloc(Hn * 4);
    float* shiftA  = (float*)alloc(Hn * 4);
    float* pooled  = (float*)alloc(Gn * Hn * 4);
    float* cnt     = (float*)alloc(Gn * 4);
    float* pfinal  = (float*)alloc(Gn * Hn * 4);
    ushort* W1T    = (ushort*)alloc((size_t)Hn * DINn * 2);
    ushort* W2T    = (ushort*)alloc((size_t)Hn * Hn * 2);
    ushort* W3T    = (ushort*)alloc((size_t)Hn * Hn * 2);

    const int TB = 256;
    const int EB = (En + TB - 1) / TB;
    const int NB = (Nn + TB - 1) / TB;

    // ---- graph prep + weight prep ----
    hipMemsetAsync(deg, 0, Nn * 4, stream);
    hipMemsetAsync(counts, 0, Nn * 4, stream);
    k_deg<<<EB, TB, 0, stream>>>(col, eattr, deg);
    k_dinv<<<NB, TB, 0, stream>>>(deg, dinv, dinv2);
    k_norm_count<<<EB, TB, 0, stream>>>(row, col, eattr, dinv, normE, counts);
    k_scan<<<1, 1024, 0, stream>>>(counts, offsets, cursor);
    k_fill<<<EB, TB, 0, stream>>>(row, col, normE, cursor, csr_row, csr_w);
    k_wt<<<dim3(DINn / 32, Hn / 32), dim3(32, 8), 0, stream>>>(W1, W1T, DINn);
    k_wt<<<dim3(Hn / 32, Hn / 32), dim3(32, 8), 0, stream>>>(W2, W2T, Hn);
    k_wt<<<dim3(Hn / 32, Hn / 32), dim3(32, 8), 0, stream>>>(W3, W3T, Hn);

    dim3 gg((Nn + GBM - 1) / GBM, 2);

    // ---- layer 1 ----
    k_gemm_mfma<<<gg, 256, 0, stream>>>(x, W1T, xw, Nn, DINn, nullptr, nullptr);
    k_agg<<<Nn, Hn, 0, stream>>>(xw, offsets, csr_row, csr_w, dinv2, b1, hbuf, 1);
    hipMemsetAsync(stats, 0, 2 * Hn * 4, stream);
    k_bnstats<<<256, Hn, 0, stream>>>(hbuf, stats);
    k_bnfinal<<<1, Hn, 0, stream>>>(stats, g1, be1, scaleA, shiftA);

    // ---- layer 2 ----
    k_gemm_mfma<<<gg, 256, 0, stream>>>(hbuf, W2T, xw, Nn, Hn, scaleA, shiftA);
    k_agg<<<Nn, Hn, 0, stream>>>(xw, offsets, csr_row, csr_w, dinv2, b2, hbuf, 1);
    hipMemsetAsync(stats, 0, 2 * Hn * 4, stream);
    k_bnstats<<<256, Hn, 0, stream>>>(hbuf, stats);
    k_bnfinal<<<1, Hn, 0, stream>>>(stats, g2, be2, scaleA, shiftA);

    // ---- layer 3 ----
    k_gemm_mfma<<<gg, 256, 0, stream>>>(hbuf, W3T, xw, Nn, Hn, scaleA, shiftA);
    k_agg<<<Nn, Hn, 0, stream>>>(xw, offsets, csr_row, csr_w, dinv2, b3, hbuf, 0);
    hipMemsetAsync(stats, 0, 2 * Hn * 4, stream);
    k_bnstats<<<256, Hn, 0, stream>>>(hbuf, stats);
    k_bnfinal<<<1, Hn, 0, stream>>>(stats, g3, be3, scaleA, shiftA);

    // ---- pooling ----
    hipMemsetAsync(pooled, 0, Gn * Hn * 4, stream);
    hipMemsetAsync(cnt, 0, Gn * 4, stream);
    k_cnt<<<NB, TB, 0, stream>>>(batch, cnt);
    k_pool<<<Nn, Hn, 0, stream>>>(hbuf, batch, scaleA, shiftA, pooled);

    // ---- head ----
    k_head1<<<Gn, Hn, 0, stream>>>(seq_emb, fc1_w, fc1_b, pooled, cnt, pfinal);
    k_head2<<<Gn, 512, 0, stream>>>(pfinal, lin_w, lin_b, out);
}

// Round 3
// 776.646 us; speedup vs baseline: 1.5013x; 1.1688x over previous
//
#include <hip/hip_runtime.h>
#include <hip/hip_bf16.h>
#include <math.h>

#define Nn 20000
#define En 320000
#define Gn 16
#define DINn 1280
#define Hn 256
#define Cn 500
#define EPSn 1e-5f

typedef __attribute__((ext_vector_type(8))) short bf16x8;
typedef __attribute__((ext_vector_type(4))) float f32x4;

// ---------------- degree / norm / CSR build ----------------

__global__ void k_deg(const int* col, const float* ew, float* deg) {
    int e = blockIdx.x * blockDim.x + threadIdx.x;
    if (e < En) atomicAdd(&deg[col[e]], ew[e]);
}

__global__ void k_dinv(const float* deg, float* dinv, float* dinv2) {
    int i = blockIdx.x * blockDim.x + threadIdx.x;
    if (i < Nn) {
        float d = deg[i] + 1.0f;
        float r = rsqrtf(d);
        dinv[i] = r;
        dinv2[i] = 1.0f / d;
    }
}

__global__ void k_norm_count(const int* row, const int* col, const float* ew,
                             const float* dinv, float* normE, int* counts) {
    int e = blockIdx.x * blockDim.x + threadIdx.x;
    if (e < En) {
        int r = row[e], c = col[e];
        normE[e] = dinv[r] * ew[e] * dinv[c];
        atomicAdd(&counts[c], 1);
    }
}

// single-block exclusive scan over counts -> offsets, cursor
__global__ void k_scan(const int* counts, int* offsets, int* cursor) {
    __shared__ int sdata[1024];
    __shared__ int s_running;
    int tid = threadIdx.x;
    if (tid == 0) s_running = 0;
    __syncthreads();
    for (int base = 0; base < Nn; base += 1024) {
        int i = base + tid;
        int v = (i < Nn) ? counts[i] : 0;
        sdata[tid] = v;
        __syncthreads();
        #pragma unroll
        for (int offi = 1; offi < 1024; offi <<= 1) {
            int t = (tid >= offi) ? sdata[tid - offi] : 0;
            __syncthreads();
            sdata[tid] += t;
            __syncthreads();
        }
        int incl = sdata[tid];
        int excl = incl - v;
        if (i < Nn) {
            int o = s_running + excl;
            offsets[i] = o;
            cursor[i] = o;
        }
        __syncthreads();
        if (tid == 1023) s_running += sdata[1023];
        __syncthreads();
    }
    if (tid == 0) offsets[Nn] = s_running;
}

__global__ void k_fill(const int* row, const int* col, const float* normE,
                       int* cursor, int* csr_row, float* csr_w) {
    int e = blockIdx.x * blockDim.x + threadIdx.x;
    if (e < En) {
        int c = col[e];
        int p = atomicAdd(&cursor[c], 1);
        csr_row[p] = row[e];
        csr_w[p] = normE[e];
    }
}

// ---------------- group bounds from sorted batch (no atomics) ----------------

__global__ void k_gbounds(const int* __restrict__ batch, int* __restrict__ gstart) {
    int i = blockIdx.x * blockDim.x + threadIdx.x;
    if (i >= Nn) return;
    int b = batch[i];
    if (i == 0) {
        for (int g = 0; g <= b; g++) gstart[g] = 0;
    } else {
        int pb = batch[i - 1];
        for (int g = pb + 1; g <= b; g++) gstart[g] = i;
    }
    if (i == Nn - 1) {
        for (int g = b + 1; g <= Gn; g++) gstart[g] = Nn;
    }
}

// ---------------- weight transpose + bf16 convert: WT[n][k] = bf16(W[k][n]) ----------------

__global__ __launch_bounds__(256) void k_wt(const float* __restrict__ W,
                                            ushort* __restrict__ WT, int K) {
    __shared__ float tile[32][33];
    int k0 = blockIdx.x * 32, n0 = blockIdx.y * 32;
    int tx = threadIdx.x, ty = threadIdx.y;   // (32, 8)
    #pragma unroll
    for (int i = 0; i < 32; i += 8)
        tile[ty + i][tx] = W[(size_t)(k0 + ty + i) * Hn + n0 + tx];
    __syncthreads();
    #pragma unroll
    for (int i = 0; i < 32; i += 8) {
        __hip_bfloat16 h = __float2bfloat16(tile[tx][ty + i]);
        WT[(size_t)(n0 + ty + i) * K + k0 + tx] = *reinterpret_cast<ushort*>(&h);
    }
}

// ---------------- MFMA GEMM: C[M x 256] = bf16(scale*A+shift) @ bf16(W) ----------------

#define GBM 128
#define GBK 32

__global__ __launch_bounds__(256) void k_gemm_mfma(
    const float* __restrict__ A, const ushort* __restrict__ BT,
    float* __restrict__ Cmat, int M, int K,
    const float* __restrict__ scale, const float* __restrict__ shift)
{
    __shared__ ushort Asl[128][40];
    __shared__ ushort Bsl[128][40];
    const int bm = blockIdx.x * GBM;
    const int bn = blockIdx.y * 128;
    const int tid = threadIdx.x;
    const int lane = tid & 63;
    const int wid = tid >> 6;
    const int wm = wid >> 1, wn = wid & 1;
    const int l15 = lane & 15, l16 = lane >> 4;

    const int srow = tid >> 1;
    const int shalf = tid & 1;
    const bool avalid = (bm + srow) < M;

    f32x4 acc[4][4] = {};

    for (int k0 = 0; k0 < K; k0 += GBK) {
        ushort tmpa[16];
        if (avalid) {
            const float4* ap = reinterpret_cast<const float4*>(
                &A[(size_t)(bm + srow) * K + k0 + shalf * 16]);
            #pragma unroll
            for (int q = 0; q < 4; q++) {
                float4 f = ap[q];
                if (scale) {
                    const float4 s = reinterpret_cast<const float4*>(&scale[k0 + shalf * 16])[q];
                    const float4 t = reinterpret_cast<const float4*>(&shift[k0 + shalf * 16])[q];
                    f.x = f.x * s.x + t.x; f.y = f.y * s.y + t.y;
                    f.z = f.z * s.z + t.z; f.w = f.w * s.w + t.w;
                }
                __hip_bfloat16 h0 = __float2bfloat16(f.x), h1 = __float2bfloat16(f.y),
                               h2 = __float2bfloat16(f.z), h3 = __float2bfloat16(f.w);
                tmpa[q * 4 + 0] = *reinterpret_cast<ushort*>(&h0);
                tmpa[q * 4 + 1] = *reinterpret_cast<ushort*>(&h1);
                tmpa[q * 4 + 2] = *reinterpret_cast<ushort*>(&h2);
                tmpa[q * 4 + 3] = *reinterpret_cast<ushort*>(&h3);
            }
        } else {
            #pragma unroll
            for (int q = 0; q < 16; q++) tmpa[q] = 0;
        }
        *reinterpret_cast<uint4*>(&Asl[srow][shalf * 16]) = *reinterpret_cast<uint4*>(&tmpa[0]);
        *reinterpret_cast<uint4*>(&Asl[srow][shalf * 16 + 8]) = *reinterpret_cast<uint4*>(&tmpa[8]);

        const uint4* bp = reinterpret_cast<const uint4*>(
            &BT[(size_t)(bn + srow) * K + k0 + shalf * 16]);
        uint4 b0 = bp[0], b1 = bp[1];
        *reinterpret_cast<uint4*>(&Bsl[srow][shalf * 16]) = b0;
        *reinterpret_cast<uint4*>(&Bsl[srow][shalf * 16 + 8]) = b1;

        __syncthreads();

        bf16x8 afr[4], bfr[4];
        #pragma unroll
        for (int i = 0; i < 4; i++)
            afr[i] = *reinterpret_cast<const bf16x8*>(&Asl[wm * 64 + i * 16 + l15][l16 * 8]);
        #pragma unroll
        for (int j = 0; j < 4; j++)
            bfr[j] = *reinterpret_cast<const bf16x8*>(&Bsl[wn * 64 + j * 16 + l15][l16 * 8]);
        #pragma unroll
        for (int i = 0; i < 4; i++)
            #pragma unroll
            for (int j = 0; j < 4; j++)
                acc[i][j] = __builtin_amdgcn_mfma_f32_16x16x32_bf16(afr[i], bfr[j], acc[i][j], 0, 0, 0);

        __syncthreads();
    }

    #pragma unroll
    for (int i = 0; i < 4; i++) {
        #pragma unroll
        for (int r = 0; r < 4; r++) {
            int grow = bm + wm * 64 + i * 16 + l16 * 4 + r;
            if (grow < M) {
                #pragma unroll
                for (int j = 0; j < 4; j++)
                    Cmat[(size_t)grow * Hn + bn + wn * 64 + j * 16 + l15] = acc[i][j][r];
            }
        }
    }
}

// ---------------- aggregation (one node per block) ----------------

__global__ __launch_bounds__(256) void k_agg(const float* __restrict__ xw,
                                             const int* __restrict__ offsets,
                                             const int* __restrict__ csr_row,
                                             const float* __restrict__ csr_w,
                                             const float* __restrict__ dinv2,
                                             const float* __restrict__ bias,
                                             float* __restrict__ outp, int do_relu) {
    int i = blockIdx.x;
    int h = threadIdx.x;
    int s = offsets[i], e = offsets[i + 1];
    float acc = 0.0f;
    for (int k = s; k < e; k++) {
        int r = csr_row[k];
        float w = csr_w[k];
        acc += w * xw[(size_t)r * Hn + h];
    }
    acc += dinv2[i] * xw[(size_t)i * Hn + h];
    acc += bias[h];
    if (do_relu) acc = fmaxf(acc, 0.0f);
    outp[(size_t)i * Hn + h] = acc;
}

// ---------------- batch-norm stats ----------------

__global__ __launch_bounds__(256) void k_bnstats(const float* __restrict__ h, float* __restrict__ stats) {
    int f = threadIdx.x;
    float s = 0.0f, ss = 0.0f;
    for (int i = blockIdx.x; i < Nn; i += gridDim.x) {
        float v = h[(size_t)i * Hn + f];
        s += v;
        ss += v * v;
    }
    atomicAdd(&stats[f], s);
    atomicAdd(&stats[Hn + f], ss);
}

__global__ void k_bnfinal(const float* stats, const float* g, const float* be,
                          float* scaleA, float* shiftA) {
    int f = threadIdx.x;
    float mean = stats[f] / (float)Nn;
    float var = stats[Hn + f] / (float)Nn - mean * mean;
    float a = g[f] * rsqrtf(var + EPSn);
    scaleA[f] = a;
    shiftA[f] = be[f] - mean * a;
}

// ---------------- pooling: segmented sums over contiguous batch ranges ----------------

#define PCH 8

__global__ __launch_bounds__(256) void k_pool2(const float* __restrict__ h,
                                               const int* __restrict__ gstart,
                                               const float* __restrict__ scaleA,
                                               const float* __restrict__ shiftA,
                                               float* __restrict__ pooled) {
    int g = blockIdx.x;        // 16
    int chunk = blockIdx.y;    // PCH
    int f = threadIdx.x;       // 256
    int s = gstart[g], e = gstart[g + 1];
    int len = e - s;
    if (len <= 0) return;
    int per = (len + PCH - 1) / PCH;
    int cs = s + chunk * per;
    int ce = cs + per; if (ce > e) ce = e;
    if (cs >= ce) return;
    float sc = scaleA[f], sh = shiftA[f];
    float acc = 0.0f;
    for (int i = cs; i < ce; i++)
        acc += h[(size_t)i * Hn + f] * sc + sh;
    atomicAdd(&pooled[g * Hn + f], acc);
}

// ---------------- head ----------------

__global__ __launch_bounds__(256) void k_head1(const float* __restrict__ seq_emb,
                                               const float* __restrict__ fc1_w,
                                               const float* __restrict__ fc1_b,
                                               const float* __restrict__ pooled,
                                               const int* __restrict__ gstart,
                                               float* __restrict__ pfinal) {
    int gidx = blockIdx.x;   // 16
    int j = threadIdx.x;     // 256
    float acc = fc1_b[j];
    const float* se = &seq_emb[(size_t)gidx * DINn];
    #pragma unroll 8
    for (int k = 0; k < DINn; k++)
        acc += se[k] * fc1_w[(size_t)k * Hn + j];
    float cntf = (float)(gstart[gidx + 1] - gstart[gidx]);
    cntf = fmaxf(cntf, 1.0f);
    pfinal[gidx * Hn + j] = pooled[gidx * Hn + j] / cntf + acc;
}

__global__ __launch_bounds__(512) void k_head2(const float* __restrict__ pfinal,
                                               const float* __restrict__ lin_w,
                                               const float* __restrict__ lin_b,
                                               float* __restrict__ out) {
    int gidx = blockIdx.x;   // 16
    int c = threadIdx.x;     // 512 (guard 500)
    if (c >= Cn) return;
    float acc = lin_b[c];
    const float* p = &pfinal[gidx * Hn];
    #pragma unroll 8
    for (int k = 0; k < Hn; k++)
        acc += p[k] * lin_w[(size_t)k * Cn + c];
    out[gidx * Cn + c] = 1.0f / (1.0f + expf(-acc));
}

// ---------------- launch ----------------

extern "C" void kernel_launch(void* const* d_in, const int* in_sizes, int n_in,
                              void* d_out, int out_size, void* d_ws, size_t ws_size,
                              hipStream_t stream) {
    const float* x        = (const float*)d_in[0];
    const int*   eidx     = (const int*)d_in[1];
    const float* eattr    = (const float*)d_in[2];
    const int*   batch    = (const int*)d_in[3];
    const float* seq_emb  = (const float*)d_in[4];
    const float* W1 = (const float*)d_in[5];
    const float* b1 = (const float*)d_in[6];
    const float* g1 = (const float*)d_in[7];
    const float* be1 = (const float*)d_in[8];
    const float* W2 = (const float*)d_in[9];
    const float* b2 = (const float*)d_in[10];
    const float* g2 = (const float*)d_in[11];
    const float* be2 = (const float*)d_in[12];
    const float* W3 = (const float*)d_in[13];
    const float* b3 = (const float*)d_in[14];
    const float* g3 = (const float*)d_in[15];
    const float* be3 = (const float*)d_in[16];
    const float* fc1_w = (const float*)d_in[17];
    const float* fc1_b = (const float*)d_in[18];
    const float* lin_w = (const float*)d_in[19];
    const float* lin_b = (const float*)d_in[20];
    float* out = (float*)d_out;

    const int* row = eidx;
    const int* col = eidx + En;

    char* ws = (char*)d_ws;
    size_t off = 0;
    auto alloc = [&](size_t bytes) -> char* {
        char* p = ws + off;
        off += (bytes + 255) & ~(size_t)255;
        return p;
    };
    float* xw      = (float*)alloc((size_t)Nn * Hn * 4);
    float* hbuf    = (float*)alloc((size_t)Nn * Hn * 4);
    float* deg     = (float*)alloc(Nn * 4);
    int*   counts  = (int*)alloc(Nn * 4);
    float* dinv    = (float*)alloc(Nn * 4);
    float* dinv2   = (float*)alloc(Nn * 4);
    float* normE   = (float*)alloc(En * 4);
    int*   offsets = (int*)alloc((Nn + 1) * 4);
    int*   cursor  = (int*)alloc(Nn * 4);
    int*   csr_row = (int*)alloc(En * 4);
    float* csr_w   = (float*)alloc(En * 4);
    float* stats   = (float*)alloc(2 * Hn * 4);
    float* scaleA  = (float*)alloc(Hn * 4);
    float* shiftA  = (float*)alloc(Hn * 4);
    float* pooled  = (float*)alloc(Gn * Hn * 4);
    int*   gstart  = (int*)alloc((Gn + 1) * 4);
    float* pfinal  = (float*)alloc(Gn * Hn * 4);
    ushort* W1T    = (ushort*)alloc((size_t)Hn * DINn * 2);
    ushort* W2T    = (ushort*)alloc((size_t)Hn * Hn * 2);
    ushort* W3T    = (ushort*)alloc((size_t)Hn * Hn * 2);

    const int TB = 256;
    const int EB = (En + TB - 1) / TB;
    const int NB = (Nn + TB - 1) / TB;

    // ---- graph prep + weight prep ----
    hipMemsetAsync(deg, 0, Nn * 4, stream);
    hipMemsetAsync(counts, 0, Nn * 4, stream);
    k_deg<<<EB, TB, 0, stream>>>(col, eattr, deg);
    k_dinv<<<NB, TB, 0, stream>>>(deg, dinv, dinv2);
    k_norm_count<<<EB, TB, 0, stream>>>(row, col, eattr, dinv, normE, counts);
    k_scan<<<1, 1024, 0, stream>>>(counts, offsets, cursor);
    k_fill<<<EB, TB, 0, stream>>>(row, col, normE, cursor, csr_row, csr_w);
    k_gbounds<<<NB, TB, 0, stream>>>(batch, gstart);
    k_wt<<<dim3(DINn / 32, Hn / 32), dim3(32, 8), 0, stream>>>(W1, W1T, DINn);
    k_wt<<<dim3(Hn / 32, Hn / 32), dim3(32, 8), 0, stream>>>(W2, W2T, Hn);
    k_wt<<<dim3(Hn / 32, Hn / 32), dim3(32, 8), 0, stream>>>(W3, W3T, Hn);

    dim3 gg((Nn + GBM - 1) / GBM, 2);

    // ---- layer 1 ----
    k_gemm_mfma<<<gg, 256, 0, stream>>>(x, W1T, xw, Nn, DINn, nullptr, nullptr);
    k_agg<<<Nn, Hn, 0, stream>>>(xw, offsets, csr_row, csr_w, dinv2, b1, hbuf, 1);
    hipMemsetAsync(stats, 0, 2 * Hn * 4, stream);
    k_bnstats<<<64, Hn, 0, stream>>>(hbuf, stats);
    k_bnfinal<<<1, Hn, 0, stream>>>(stats, g1, be1, scaleA, shiftA);

    // ---- layer 2 ----
    k_gemm_mfma<<<gg, 256, 0, stream>>>(hbuf, W2T, xw, Nn, Hn, scaleA, shiftA);
    k_agg<<<Nn, Hn, 0, stream>>>(xw, offsets, csr_row, csr_w, dinv2, b2, hbuf, 1);
    hipMemsetAsync(stats, 0, 2 * Hn * 4, stream);
    k_bnstats<<<64, Hn, 0, stream>>>(hbuf, stats);
    k_bnfinal<<<1, Hn, 0, stream>>>(stats, g2, be2, scaleA, shiftA);

    // ---- layer 3 ----
    k_gemm_mfma<<<gg, 256, 0, stream>>>(hbuf, W3T, xw, Nn, Hn, scaleA, shiftA);
    k_agg<<<Nn, Hn, 0, stream>>>(xw, offsets, csr_row, csr_w, dinv2, b3, hbuf, 0);
    hipMemsetAsync(stats, 0, 2 * Hn * 4, stream);
    k_bnstats<<<64, Hn, 0, stream>>>(hbuf, stats);
    k_bnfinal<<<1, Hn, 0, stream>>>(stats, g3, be3, scaleA, shiftA);

    // ---- pooling ----
    hipMemsetAsync(pooled, 0, Gn * Hn * 4, stream);
    k_pool2<<<dim3(Gn, PCH), Hn, 0, stream>>>(hbuf, gstart, scaleA, shiftA, pooled);

    // ---- head ----
    k_head1<<<Gn, Hn, 0, stream>>>(seq_emb, fc1_w, fc1_b, pooled, gstart, pfinal);
    k_head2<<<Gn, 512, 0, stream>>>(pfinal, lin_w, lin_b, out);
}

// Round 4
// 475.978 us; speedup vs baseline: 2.4497x; 1.6317x over previous
//
#include <hip/hip_runtime.h>
#include <hip/hip_bf16.h>
#include <math.h>

#define Nn 20000
#define En 320000
#define Gn 16
#define DINn 1280
#define Hn 256
#define Cn 500
#define EPSn 1e-5f
#define BNB 1024

typedef __attribute__((ext_vector_type(8))) short bf16x8;
typedef __attribute__((ext_vector_type(4))) float f32x4;

// ---------------- degree / norm / CSR build ----------------

__global__ void k_deg(const int* col, const float* ew, float* deg) {
    int e = blockIdx.x * blockDim.x + threadIdx.x;
    if (e < En) atomicAdd(&deg[col[e]], ew[e]);
}

__global__ void k_dinv(const float* deg, float* dinv, float* dinv2) {
    int i = blockIdx.x * blockDim.x + threadIdx.x;
    if (i < Nn) {
        float d = deg[i] + 1.0f;
        float r = rsqrtf(d);
        dinv[i] = r;
        dinv2[i] = 1.0f / d;
    }
}

__global__ void k_norm_count(const int* row, const int* col, const float* ew,
                             const float* dinv, float* normE, int* counts) {
    int e = blockIdx.x * blockDim.x + threadIdx.x;
    if (e < En) {
        int r = row[e], c = col[e];
        normE[e] = dinv[r] * ew[e] * dinv[c];
        atomicAdd(&counts[c], 1);
    }
}

// single-block exclusive scan over counts -> offsets, cursor
__global__ void k_scan(const int* counts, int* offsets, int* cursor) {
    __shared__ int sdata[1024];
    __shared__ int s_running;
    int tid = threadIdx.x;
    if (tid == 0) s_running = 0;
    __syncthreads();
    for (int base = 0; base < Nn; base += 1024) {
        int i = base + tid;
        int v = (i < Nn) ? counts[i] : 0;
        sdata[tid] = v;
        __syncthreads();
        #pragma unroll
        for (int offi = 1; offi < 1024; offi <<= 1) {
            int t = (tid >= offi) ? sdata[tid - offi] : 0;
            __syncthreads();
            sdata[tid] += t;
            __syncthreads();
        }
        int incl = sdata[tid];
        int excl = incl - v;
        if (i < Nn) {
            int o = s_running + excl;
            offsets[i] = o;
            cursor[i] = o;
        }
        __syncthreads();
        if (tid == 1023) s_running += sdata[1023];
        __syncthreads();
    }
    if (tid == 0) offsets[Nn] = s_running;
}

__global__ void k_fill(const int* row, const int* col, const float* normE,
                       int* cursor, int* csr_row, float* csr_w) {
    int e = blockIdx.x * blockDim.x + threadIdx.x;
    if (e < En) {
        int c = col[e];
        int p = atomicAdd(&cursor[c], 1);
        csr_row[p] = row[e];
        csr_w[p] = normE[e];
    }
}

// ---------------- group bounds from sorted batch (no atomics) ----------------

__global__ void k_gbounds(const int* __restrict__ batch, int* __restrict__ gstart) {
    int i = blockIdx.x * blockDim.x + threadIdx.x;
    if (i >= Nn) return;
    int b = batch[i];
    if (i == 0) {
        for (int g = 0; g <= b; g++) gstart[g] = 0;
    } else {
        int pb = batch[i - 1];
        for (int g = pb + 1; g <= b; g++) gstart[g] = i;
    }
    if (i == Nn - 1) {
        for (int g = b + 1; g <= Gn; g++) gstart[g] = Nn;
    }
}

// ---------------- weight transpose + bf16 convert ----------------

__global__ __launch_bounds__(256) void k_wt(const float* __restrict__ W,
                                            ushort* __restrict__ WT, int K) {
    __shared__ float tile[32][33];
    int k0 = blockIdx.x * 32, n0 = blockIdx.y * 32;
    int tx = threadIdx.x, ty = threadIdx.y;   // (32, 8)
    #pragma unroll
    for (int i = 0; i < 32; i += 8)
        tile[ty + i][tx] = W[(size_t)(k0 + ty + i) * Hn + n0 + tx];
    __syncthreads();
    #pragma unroll
    for (int i = 0; i < 32; i += 8) {
        __hip_bfloat16 h = __float2bfloat16(tile[tx][ty + i]);
        WT[(size_t)(n0 + ty + i) * K + k0 + tx] = *reinterpret_cast<ushort*>(&h);
    }
}

// ---------------- MFMA GEMM ----------------

#define GBM 128
#define GBK 32

__global__ __launch_bounds__(256) void k_gemm_mfma(
    const float* __restrict__ A, const ushort* __restrict__ BT,
    float* __restrict__ Cmat, int M, int K,
    const float* __restrict__ scale, const float* __restrict__ shift)
{
    __shared__ ushort Asl[128][40];
    __shared__ ushort Bsl[128][40];
    const int bm = blockIdx.x * GBM;
    const int bn = blockIdx.y * 128;
    const int tid = threadIdx.x;
    const int lane = tid & 63;
    const int wid = tid >> 6;
    const int wm = wid >> 1, wn = wid & 1;
    const int l15 = lane & 15, l16 = lane >> 4;

    const int srow = tid >> 1;
    const int shalf = tid & 1;
    const bool avalid = (bm + srow) < M;

    f32x4 acc[4][4] = {};

    for (int k0 = 0; k0 < K; k0 += GBK) {
        ushort tmpa[16];
        if (avalid) {
            const float4* ap = reinterpret_cast<const float4*>(
                &A[(size_t)(bm + srow) * K + k0 + shalf * 16]);
            #pragma unroll
            for (int q = 0; q < 4; q++) {
                float4 f = ap[q];
                if (scale) {
                    const float4 s = reinterpret_cast<const float4*>(&scale[k0 + shalf * 16])[q];
                    const float4 t = reinterpret_cast<const float4*>(&shift[k0 + shalf * 16])[q];
                    f.x = f.x * s.x + t.x; f.y = f.y * s.y + t.y;
                    f.z = f.z * s.z + t.z; f.w = f.w * s.w + t.w;
                }
                __hip_bfloat16 h0 = __float2bfloat16(f.x), h1 = __float2bfloat16(f.y),
                               h2 = __float2bfloat16(f.z), h3 = __float2bfloat16(f.w);
                tmpa[q * 4 + 0] = *reinterpret_cast<ushort*>(&h0);
                tmpa[q * 4 + 1] = *reinterpret_cast<ushort*>(&h1);
                tmpa[q * 4 + 2] = *reinterpret_cast<ushort*>(&h2);
                tmpa[q * 4 + 3] = *reinterpret_cast<ushort*>(&h3);
            }
        } else {
            #pragma unroll
            for (int q = 0; q < 16; q++) tmpa[q] = 0;
        }
        *reinterpret_cast<uint4*>(&Asl[srow][shalf * 16]) = *reinterpret_cast<uint4*>(&tmpa[0]);
        *reinterpret_cast<uint4*>(&Asl[srow][shalf * 16 + 8]) = *reinterpret_cast<uint4*>(&tmpa[8]);

        const uint4* bp = reinterpret_cast<const uint4*>(
            &BT[(size_t)(bn + srow) * K + k0 + shalf * 16]);
        uint4 b0 = bp[0], b1 = bp[1];
        *reinterpret_cast<uint4*>(&Bsl[srow][shalf * 16]) = b0;
        *reinterpret_cast<uint4*>(&Bsl[srow][shalf * 16 + 8]) = b1;

        __syncthreads();

        bf16x8 afr[4], bfr[4];
        #pragma unroll
        for (int i = 0; i < 4; i++)
            afr[i] = *reinterpret_cast<const bf16x8*>(&Asl[wm * 64 + i * 16 + l15][l16 * 8]);
        #pragma unroll
        for (int j = 0; j < 4; j++)
            bfr[j] = *reinterpret_cast<const bf16x8*>(&Bsl[wn * 64 + j * 16 + l15][l16 * 8]);
        #pragma unroll
        for (int i = 0; i < 4; i++)
            #pragma unroll
            for (int j = 0; j < 4; j++)
                acc[i][j] = __builtin_amdgcn_mfma_f32_16x16x32_bf16(afr[i], bfr[j], acc[i][j], 0, 0, 0);

        __syncthreads();
    }

    #pragma unroll
    for (int i = 0; i < 4; i++) {
        #pragma unroll
        for (int r = 0; r < 4; r++) {
            int grow = bm + wm * 64 + i * 16 + l16 * 4 + r;
            if (grow < M) {
                #pragma unroll
                for (int j = 0; j < 4; j++)
                    Cmat[(size_t)grow * Hn + bn + wn * 64 + j * 16 + l15] = acc[i][j][r];
            }
        }
    }
}

// ---------------- aggregation: one wave per node, float4 lanes ----------------

__global__ __launch_bounds__(256) void k_agg(const float* __restrict__ xw,
                                             const int* __restrict__ offsets,
                                             const int* __restrict__ csr_row,
                                             const float* __restrict__ csr_w,
                                             const float* __restrict__ dinv2,
                                             const float* __restrict__ bias,
                                             float* __restrict__ outp, int do_relu) {
    int node = blockIdx.x * 4 + (threadIdx.x >> 6);
    int lane = threadIdx.x & 63;
    if (node >= Nn) return;
    int s = offsets[node], e = offsets[node + 1];
    const float4* xw4 = reinterpret_cast<const float4*>(xw);  // row stride: 64 float4
    float4 acc = {0.0f, 0.0f, 0.0f, 0.0f};
    for (int k = s; k < e; k++) {
        int r = csr_row[k];
        float w = csr_w[k];
        float4 v = xw4[(size_t)r * 64 + lane];
        acc.x += w * v.x; acc.y += w * v.y; acc.z += w * v.z; acc.w += w * v.w;
    }
    float d2 = dinv2[node];
    float4 v = xw4[(size_t)node * 64 + lane];
    acc.x += d2 * v.x; acc.y += d2 * v.y; acc.z += d2 * v.z; acc.w += d2 * v.w;
    float4 b = reinterpret_cast<const float4*>(bias)[lane];
    acc.x += b.x; acc.y += b.y; acc.z += b.z; acc.w += b.w;
    if (do_relu) {
        acc.x = fmaxf(acc.x, 0.0f); acc.y = fmaxf(acc.y, 0.0f);
        acc.z = fmaxf(acc.z, 0.0f); acc.w = fmaxf(acc.w, 0.0f);
    }
    reinterpret_cast<float4*>(outp)[(size_t)node * 64 + lane] = acc;
}

// ---------------- batch-norm stats: 3-stage ----------------

__global__ __launch_bounds__(256) void k_bnpart(const float* __restrict__ h,
                                                float* __restrict__ partial) {
    int f = threadIdx.x;
    int blk = blockIdx.x;
    float s = 0.0f, ss = 0.0f;
    for (int i = blk; i < Nn; i += BNB) {
        float v = h[(size_t)i * Hn + f];
        s += v;
        ss += v * v;
    }
    partial[(size_t)blk * 512 + f] = s;
    partial[(size_t)blk * 512 + 256 + f] = ss;
}

__global__ __launch_bounds__(256) void k_bnred(const float* __restrict__ partial,
                                               float* __restrict__ stats) {
    int f = threadIdx.x;
    int b0 = blockIdx.x * 64;
    float s = 0.0f, ss = 0.0f;
    for (int j = 0; j < 64; j++) {
        const float* p = &partial[(size_t)(b0 + j) * 512];
        s += p[f];
        ss += p[256 + f];
    }
    atomicAdd(&stats[f], s);
    atomicAdd(&stats[Hn + f], ss);
}

__global__ void k_bnfinal(const float* stats, const float* g, const float* be,
                          float* scaleA, float* shiftA) {
    int f = threadIdx.x;
    float mean = stats[f] / (float)Nn;
    float var = stats[Hn + f] / (float)Nn - mean * mean;
    float a = g[f] * rsqrtf(var + EPSn);
    scaleA[f] = a;
    shiftA[f] = be[f] - mean * a;
}

// ---------------- pooling: segmented sums over contiguous batch ranges ----------------

#define PCH 8

__global__ __launch_bounds__(256) void k_pool2(const float* __restrict__ h,
                                               const int* __restrict__ gstart,
                                               const float* __restrict__ scaleA,
                                               const float* __restrict__ shiftA,
                                               float* __restrict__ pooled) {
    int g = blockIdx.x;
    int chunk = blockIdx.y;
    int f = threadIdx.x;
    int s = gstart[g], e = gstart[g + 1];
    int len = e - s;
    if (len <= 0) return;
    int per = (len + PCH - 1) / PCH;
    int cs = s + chunk * per;
    int ce = cs + per; if (ce > e) ce = e;
    if (cs >= ce) return;
    float sc = scaleA[f], sh = shiftA[f];
    float acc = 0.0f;
    for (int i = cs; i < ce; i++)
        acc += h[(size_t)i * Hn + f] * sc + sh;
    atomicAdd(&pooled[g * Hn + f], acc);
}

// ---------------- head ----------------

__global__ __launch_bounds__(256) void k_head1init(const float* __restrict__ pooled,
                                                   const int* __restrict__ gstart,
                                                   const float* __restrict__ fc1_b,
                                                   float* __restrict__ pfinal) {
    int gidx = blockIdx.x;
    int j = threadIdx.x;
    float cntf = (float)(gstart[gidx + 1] - gstart[gidx]);
    cntf = fmaxf(cntf, 1.0f);
    pfinal[gidx * Hn + j] = pooled[gidx * Hn + j] / cntf + fc1_b[j];
}

__global__ __launch_bounds__(256) void k_head1part(const float* __restrict__ seq_emb,
                                                   const float* __restrict__ fc1_w,
                                                   float* __restrict__ pfinal) {
    int gidx = blockIdx.x;   // 16
    int kc = blockIdx.y;     // 10 chunks of 128
    int j = threadIdx.x;     // 256
    const float* se = &seq_emb[(size_t)gidx * DINn + kc * 128];
    const float* w = &fc1_w[(size_t)kc * 128 * Hn + j];
    float acc = 0.0f;
    #pragma unroll 8
    for (int k = 0; k < 128; k++)
        acc += se[k] * w[(size_t)k * Hn];
    atomicAdd(&pfinal[gidx * Hn + j], acc);
}

__global__ __launch_bounds__(512) void k_head2(const float* __restrict__ pfinal,
                                               const float* __restrict__ lin_w,
                                               const float* __restrict__ lin_b,
                                               float* __restrict__ out) {
    int gidx = blockIdx.x;
    int c = threadIdx.x;
    if (c >= Cn) return;
    float acc = lin_b[c];
    const float* p = &pfinal[gidx * Hn];
    #pragma unroll 8
    for (int k = 0; k < Hn; k++)
        acc += p[k] * lin_w[(size_t)k * Cn + c];
    out[gidx * Cn + c] = 1.0f / (1.0f + expf(-acc));
}

// ---------------- launch ----------------

extern "C" void kernel_launch(void* const* d_in, const int* in_sizes, int n_in,
                              void* d_out, int out_size, void* d_ws, size_t ws_size,
                              hipStream_t stream) {
    const float* x        = (const float*)d_in[0];
    const int*   eidx     = (const int*)d_in[1];
    const float* eattr    = (const float*)d_in[2];
    const int*   batch    = (const int*)d_in[3];
    const float* seq_emb  = (const float*)d_in[4];
    const float* W1 = (const float*)d_in[5];
    const float* b1 = (const float*)d_in[6];
    const float* g1 = (const float*)d_in[7];
    const float* be1 = (const float*)d_in[8];
    const float* W2 = (const float*)d_in[9];
    const float* b2 = (const float*)d_in[10];
    const float* g2 = (const float*)d_in[11];
    const float* be2 = (const float*)d_in[12];
    const float* W3 = (const float*)d_in[13];
    const float* b3 = (const float*)d_in[14];
    const float* g3 = (const float*)d_in[15];
    const float* be3 = (const float*)d_in[16];
    const float* fc1_w = (const float*)d_in[17];
    const float* fc1_b = (const float*)d_in[18];
    const float* lin_w = (const float*)d_in[19];
    const float* lin_b = (const float*)d_in[20];
    float* out = (float*)d_out;

    const int* row = eidx;
    const int* col = eidx + En;

    char* ws = (char*)d_ws;
    size_t off = 0;
    auto alloc = [&](size_t bytes) -> char* {
        char* p = ws + off;
        off += (bytes + 255) & ~(size_t)255;
        return p;
    };
    float* xw      = (float*)alloc((size_t)Nn * Hn * 4);
    float* hbuf    = (float*)alloc((size_t)Nn * Hn * 4);
    float* deg     = (float*)alloc(Nn * 4);
    int*   counts  = (int*)alloc(Nn * 4);
    float* dinv    = (float*)alloc(Nn * 4);
    float* dinv2   = (float*)alloc(Nn * 4);
    float* normE   = (float*)alloc(En * 4);
    int*   offsets = (int*)alloc((Nn + 1) * 4);
    int*   cursor  = (int*)alloc(Nn * 4);
    int*   csr_row = (int*)alloc(En * 4);
    float* csr_w   = (float*)alloc(En * 4);
    float* stats   = (float*)alloc(2 * Hn * 4);
    float* scaleA  = (float*)alloc(Hn * 4);
    float* shiftA  = (float*)alloc(Hn * 4);
    float* pooled  = (float*)alloc(Gn * Hn * 4);
    int*   gstart  = (int*)alloc((Gn + 1) * 4);
    float* pfinal  = (float*)alloc(Gn * Hn * 4);
    float* partial = (float*)alloc((size_t)BNB * 512 * 4);
    ushort* W1T    = (ushort*)alloc((size_t)Hn * DINn * 2);
    ushort* W2T    = (ushort*)alloc((size_t)Hn * Hn * 2);
    ushort* W3T    = (ushort*)alloc((size_t)Hn * Hn * 2);

    const int TB = 256;
    const int EB = (En + TB - 1) / TB;
    const int NB = (Nn + TB - 1) / TB;

    // ---- graph prep + weight prep ----
    hipMemsetAsync(deg, 0, Nn * 4, stream);
    hipMemsetAsync(counts, 0, Nn * 4, stream);
    k_deg<<<EB, TB, 0, stream>>>(col, eattr, deg);
    k_dinv<<<NB, TB, 0, stream>>>(deg, dinv, dinv2);
    k_norm_count<<<EB, TB, 0, stream>>>(row, col, eattr, dinv, normE, counts);
    k_scan<<<1, 1024, 0, stream>>>(counts, offsets, cursor);
    k_fill<<<EB, TB, 0, stream>>>(row, col, normE, cursor, csr_row, csr_w);
    k_gbounds<<<NB, TB, 0, stream>>>(batch, gstart);
    k_wt<<<dim3(DINn / 32, Hn / 32), dim3(32, 8), 0, stream>>>(W1, W1T, DINn);
    k_wt<<<dim3(Hn / 32, Hn / 32), dim3(32, 8), 0, stream>>>(W2, W2T, Hn);
    k_wt<<<dim3(Hn / 32, Hn / 32), dim3(32, 8), 0, stream>>>(W3, W3T, Hn);

    dim3 gg((Nn + GBM - 1) / GBM, 2);
    const int AGB = Nn / 4;   // k_agg blocks (4 nodes per block)

    // ---- layer 1 ----
    k_gemm_mfma<<<gg, 256, 0, stream>>>(x, W1T, xw, Nn, DINn, nullptr, nullptr);
    k_agg<<<AGB, 256, 0, stream>>>(xw, offsets, csr_row, csr_w, dinv2, b1, hbuf, 1);
    hipMemsetAsync(stats, 0, 2 * Hn * 4, stream);
    k_bnpart<<<BNB, Hn, 0, stream>>>(hbuf, partial);
    k_bnred<<<BNB / 64, Hn, 0, stream>>>(partial, stats);
    k_bnfinal<<<1, Hn, 0, stream>>>(stats, g1, be1, scaleA, shiftA);

    // ---- layer 2 ----
    k_gemm_mfma<<<gg, 256, 0, stream>>>(hbuf, W2T, xw, Nn, Hn, scaleA, shiftA);
    k_agg<<<AGB, 256, 0, stream>>>(xw, offsets, csr_row, csr_w, dinv2, b2, hbuf, 1);
    hipMemsetAsync(stats, 0, 2 * Hn * 4, stream);
    k_bnpart<<<BNB, Hn, 0, stream>>>(hbuf, partial);
    k_bnred<<<BNB / 64, Hn, 0, stream>>>(partial, stats);
    k_bnfinal<<<1, Hn, 0, stream>>>(stats, g2, be2, scaleA, shiftA);

    // ---- layer 3 ----
    k_gemm_mfma<<<gg, 256, 0, stream>>>(hbuf, W3T, xw, Nn, Hn, scaleA, shiftA);
    k_agg<<<AGB, 256, 0, stream>>>(xw, offsets, csr_row, csr_w, dinv2, b3, hbuf, 0);
    hipMemsetAsync(stats, 0, 2 * Hn * 4, stream);
    k_bnpart<<<BNB, Hn, 0, stream>>>(hbuf, partial);
    k_bnred<<<BNB / 64, Hn, 0, stream>>>(partial, stats);
    k_bnfinal<<<1, Hn, 0, stream>>>(stats, g3, be3, scaleA, shiftA);

    // ---- pooling ----
    hipMemsetAsync(pooled, 0, Gn * Hn * 4, stream);
    k_pool2<<<dim3(Gn, PCH), Hn, 0, stream>>>(hbuf, gstart, scaleA, shiftA, pooled);

    // ---- head ----
    k_head1init<<<Gn, Hn, 0, stream>>>(pooled, gstart, fc1_b, pfinal);
    k_head1part<<<dim3(Gn, DINn / 128), Hn, 0, stream>>>(seq_emb, fc1_w, pfinal);
    k_head2<<<Gn, 512, 0, stream>>>(pfinal, lin_w, lin_b, out);
}

// Round 5
// 449.957 us; speedup vs baseline: 2.5914x; 1.0578x over previous
//
#include <hip/hip_runtime.h>
#include <hip/hip_bf16.h>
#include <math.h>

#define Nn 20000
#define En 320000
#define Gn 16
#define DINn 1280
#define Hn 256
#define Cn 500
#define EPSn 1e-5f
#define BNB 1024

typedef __attribute__((ext_vector_type(8))) short bf16x8;
typedef __attribute__((ext_vector_type(4))) float f32x4;

// ---------------- degree / norm / CSR build ----------------

__global__ void k_deg(const int* col, const float* ew, float* deg) {
    int e = blockIdx.x * blockDim.x + threadIdx.x;
    if (e < En) atomicAdd(&deg[col[e]], ew[e]);
}

__global__ void k_dinv(const float* deg, float* dinv, float* dinv2) {
    int i = blockIdx.x * blockDim.x + threadIdx.x;
    if (i < Nn) {
        float d = deg[i] + 1.0f;
        float r = rsqrtf(d);
        dinv[i] = r;
        dinv2[i] = 1.0f / d;
    }
}

__global__ void k_norm_count(const int* row, const int* col, const float* ew,
                             const float* dinv, float* normE, int* counts) {
    int e = blockIdx.x * blockDim.x + threadIdx.x;
    if (e < En) {
        int r = row[e], c = col[e];
        normE[e] = dinv[r] * ew[e] * dinv[c];
        atomicAdd(&counts[c], 1);
    }
}

// single-block exclusive scan over counts -> offsets, cursor
__global__ void k_scan(const int* counts, int* offsets, int* cursor) {
    __shared__ int sdata[1024];
    __shared__ int s_running;
    int tid = threadIdx.x;
    if (tid == 0) s_running = 0;
    __syncthreads();
    for (int base = 0; base < Nn; base += 1024) {
        int i = base + tid;
        int v = (i < Nn) ? counts[i] : 0;
        sdata[tid] = v;
        __syncthreads();
        #pragma unroll
        for (int offi = 1; offi < 1024; offi <<= 1) {
            int t = (tid >= offi) ? sdata[tid - offi] : 0;
            __syncthreads();
            sdata[tid] += t;
            __syncthreads();
        }
        int incl = sdata[tid];
        int excl = incl - v;
        if (i < Nn) {
            int o = s_running + excl;
            offsets[i] = o;
            cursor[i] = o;
        }
        __syncthreads();
        if (tid == 1023) s_running += sdata[1023];
        __syncthreads();
    }
    if (tid == 0) offsets[Nn] = s_running;
}

__global__ void k_fill(const int* row, const int* col, const float* normE,
                       int* cursor, int* csr_row, float* csr_w) {
    int e = blockIdx.x * blockDim.x + threadIdx.x;
    if (e < En) {
        int c = col[e];
        int p = atomicAdd(&cursor[c], 1);
        csr_row[p] = row[e];
        csr_w[p] = normE[e];
    }
}

// ---------------- group bounds from sorted batch (no atomics) ----------------

__global__ void k_gbounds(const int* __restrict__ batch, int* __restrict__ gstart) {
    int i = blockIdx.x * blockDim.x + threadIdx.x;
    if (i >= Nn) return;
    int b = batch[i];
    if (i == 0) {
        for (int g = 0; g <= b; g++) gstart[g] = 0;
    } else {
        int pb = batch[i - 1];
        for (int g = pb + 1; g <= b; g++) gstart[g] = i;
    }
    if (i == Nn - 1) {
        for (int g = b + 1; g <= Gn; g++) gstart[g] = Nn;
    }
}

// ---------------- weight transpose + bf16 convert ----------------

__global__ __launch_bounds__(256) void k_wt(const float* __restrict__ W,
                                            ushort* __restrict__ WT, int K) {
    __shared__ float tile[32][33];
    int k0 = blockIdx.x * 32, n0 = blockIdx.y * 32;
    int tx = threadIdx.x, ty = threadIdx.y;   // (32, 8)
    #pragma unroll
    for (int i = 0; i < 32; i += 8)
        tile[ty + i][tx] = W[(size_t)(k0 + ty + i) * Hn + n0 + tx];
    __syncthreads();
    #pragma unroll
    for (int i = 0; i < 32; i += 8) {
        __hip_bfloat16 h = __float2bfloat16(tile[tx][ty + i]);
        WT[(size_t)(n0 + ty + i) * K + k0 + tx] = *reinterpret_cast<ushort*>(&h);
    }
}

// ---------------- MFMA GEMM: 64x128 tile, double-buffered, prefetched ----------------

#define GBM 64
#define GBN 128
#define GBK 32

__global__ __launch_bounds__(256) void k_gemm_mfma(
    const float* __restrict__ A, const ushort* __restrict__ BT,
    float* __restrict__ Cmat, int M, int K,
    const float* __restrict__ scale, const float* __restrict__ shift)
{
    __shared__ ushort Asl[2][GBM][40];
    __shared__ ushort Bsl[2][GBN][40];
    const int bm = blockIdx.x * GBM;
    const int bn = blockIdx.y * GBN;
    const int tid = threadIdx.x;
    const int lane = tid & 63;
    const int wid = tid >> 6;
    const int wm = wid >> 1, wn = wid & 1;   // wave tile 32(M) x 64(N)
    const int l15 = lane & 15, l16 = lane >> 4;

    // A staging: 64 rows x 32 k; thread -> (row=tid>>2, 8-k chunk)
    const int arow = tid >> 2;
    const int akc = (tid & 3) * 8;
    const bool avalid = (bm + arow) < M;
    // B staging: 128 rows x 32 k; thread -> (row=tid>>1, 16-k half)
    const int brow = tid >> 1;
    const int bkh = (tid & 1) * 16;

    const int nt = K / GBK;

    f32x4 acc[2][4] = {};
    float4 fa0, fa1;
    uint4 fb0, fb1;

    auto load_regs = [&](int t) {
        int k0 = t * GBK;
        if (avalid) {
            const float4* ap = reinterpret_cast<const float4*>(
                &A[(size_t)(bm + arow) * K + k0 + akc]);
            fa0 = ap[0]; fa1 = ap[1];
        }
        const uint4* bp = reinterpret_cast<const uint4*>(
            &BT[(size_t)(bn + brow) * K + k0 + bkh]);
        fb0 = bp[0]; fb1 = bp[1];
    };

    auto store_lds = [&](int buf, int t) {
        int k0 = t * GBK;
        ushort tmpa[8];
        if (avalid) {
            float4 f0 = fa0, f1 = fa1;
            if (scale) {
                const float4 s0 = reinterpret_cast<const float4*>(&scale[k0 + akc])[0];
                const float4 s1 = reinterpret_cast<const float4*>(&scale[k0 + akc])[1];
                const float4 t0 = reinterpret_cast<const float4*>(&shift[k0 + akc])[0];
                const float4 t1 = reinterpret_cast<const float4*>(&shift[k0 + akc])[1];
                f0.x = f0.x * s0.x + t0.x; f0.y = f0.y * s0.y + t0.y;
                f0.z = f0.z * s0.z + t0.z; f0.w = f0.w * s0.w + t0.w;
                f1.x = f1.x * s1.x + t1.x; f1.y = f1.y * s1.y + t1.y;
                f1.z = f1.z * s1.z + t1.z; f1.w = f1.w * s1.w + t1.w;
            }
            __hip_bfloat16 h;
            h = __float2bfloat16(f0.x); tmpa[0] = *reinterpret_cast<ushort*>(&h);
            h = __float2bfloat16(f0.y); tmpa[1] = *reinterpret_cast<ushort*>(&h);
            h = __float2bfloat16(f0.z); tmpa[2] = *reinterpret_cast<ushort*>(&h);
            h = __float2bfloat16(f0.w); tmpa[3] = *reinterpret_cast<ushort*>(&h);
            h = __float2bfloat16(f1.x); tmpa[4] = *reinterpret_cast<ushort*>(&h);
            h = __float2bfloat16(f1.y); tmpa[5] = *reinterpret_cast<ushort*>(&h);
            h = __float2bfloat16(f1.z); tmpa[6] = *reinterpret_cast<ushort*>(&h);
            h = __float2bfloat16(f1.w); tmpa[7] = *reinterpret_cast<ushort*>(&h);
        } else {
            #pragma unroll
            for (int q = 0; q < 8; q++) tmpa[q] = 0;
        }
        *reinterpret_cast<uint4*>(&Asl[buf][arow][akc]) = *reinterpret_cast<uint4*>(&tmpa[0]);
        *reinterpret_cast<uint4*>(&Bsl[buf][brow][bkh]) = fb0;
        *reinterpret_cast<uint4*>(&Bsl[buf][brow][bkh + 8]) = fb1;
    };

    auto compute = [&](int buf) {
        bf16x8 afr[2], bfr[4];
        #pragma unroll
        for (int i = 0; i < 2; i++)
            afr[i] = *reinterpret_cast<const bf16x8*>(&Asl[buf][wm * 32 + i * 16 + l15][l16 * 8]);
        #pragma unroll
        for (int j = 0; j < 4; j++)
            bfr[j] = *reinterpret_cast<const bf16x8*>(&Bsl[buf][wn * 64 + j * 16 + l15][l16 * 8]);
        #pragma unroll
        for (int i = 0; i < 2; i++)
            #pragma unroll
            for (int j = 0; j < 4; j++)
                acc[i][j] = __builtin_amdgcn_mfma_f32_16x16x32_bf16(afr[i], bfr[j], acc[i][j], 0, 0, 0);
    };

    load_regs(0);
    store_lds(0, 0);
    __syncthreads();
    for (int t = 0; t < nt; t++) {
        int cur = t & 1;
        if (t + 1 < nt) load_regs(t + 1);
        compute(cur);
        if (t + 1 < nt) store_lds(cur ^ 1, t + 1);
        __syncthreads();
    }

    #pragma unroll
    for (int i = 0; i < 2; i++) {
        #pragma unroll
        for (int r = 0; r < 4; r++) {
            int grow = bm + wm * 32 + i * 16 + l16 * 4 + r;
            if (grow < M) {
                #pragma unroll
                for (int j = 0; j < 4; j++)
                    Cmat[(size_t)grow * Hn + bn + wn * 64 + j * 16 + l15] = acc[i][j][r];
            }
        }
    }
}

// ---------------- aggregation: one wave per node, float4 lanes ----------------

__global__ __launch_bounds__(256) void k_agg(const float* __restrict__ xw,
                                             const int* __restrict__ offsets,
                                             const int* __restrict__ csr_row,
                                             const float* __restrict__ csr_w,
                                             const float* __restrict__ dinv2,
                                             const float* __restrict__ bias,
                                             float* __restrict__ outp, int do_relu) {
    int node = blockIdx.x * 4 + (threadIdx.x >> 6);
    int lane = threadIdx.x & 63;
    if (node >= Nn) return;
    int s = offsets[node], e = offsets[node + 1];
    const float4* xw4 = reinterpret_cast<const float4*>(xw);  // row stride: 64 float4
    float4 acc = {0.0f, 0.0f, 0.0f, 0.0f};
    for (int k = s; k < e; k++) {
        int r = csr_row[k];
        float w = csr_w[k];
        float4 v = xw4[(size_t)r * 64 + lane];
        acc.x += w * v.x; acc.y += w * v.y; acc.z += w * v.z; acc.w += w * v.w;
    }
    float d2 = dinv2[node];
    float4 v = xw4[(size_t)node * 64 + lane];
    acc.x += d2 * v.x; acc.y += d2 * v.y; acc.z += d2 * v.z; acc.w += d2 * v.w;
    float4 b = reinterpret_cast<const float4*>(bias)[lane];
    acc.x += b.x; acc.y += b.y; acc.z += b.z; acc.w += b.w;
    if (do_relu) {
        acc.x = fmaxf(acc.x, 0.0f); acc.y = fmaxf(acc.y, 0.0f);
        acc.z = fmaxf(acc.z, 0.0f); acc.w = fmaxf(acc.w, 0.0f);
    }
    reinterpret_cast<float4*>(outp)[(size_t)node * 64 + lane] = acc;
}

// ---------------- batch-norm stats: 3-stage ----------------

__global__ __launch_bounds__(256) void k_bnpart(const float* __restrict__ h,
                                                float* __restrict__ partial) {
    int f = threadIdx.x;
    int blk = blockIdx.x;
    float s = 0.0f, ss = 0.0f;
    for (int i = blk; i < Nn; i += BNB) {
        float v = h[(size_t)i * Hn + f];
        s += v;
        ss += v * v;
    }
    partial[(size_t)blk * 512 + f] = s;
    partial[(size_t)blk * 512 + 256 + f] = ss;
}

__global__ __launch_bounds__(256) void k_bnred(const float* __restrict__ partial,
                                               float* __restrict__ stats) {
    int f = threadIdx.x;
    int b0 = blockIdx.x * 64;
    float s = 0.0f, ss = 0.0f;
    for (int j = 0; j < 64; j++) {
        const float* p = &partial[(size_t)(b0 + j) * 512];
        s += p[f];
        ss += p[256 + f];
    }
    atomicAdd(&stats[f], s);
    atomicAdd(&stats[Hn + f], ss);
}

__global__ void k_bnfinal(const float* stats, const float* g, const float* be,
                          float* scaleA, float* shiftA) {
    int f = threadIdx.x;
    float mean = stats[f] / (float)Nn;
    float var = stats[Hn + f] / (float)Nn - mean * mean;
    float a = g[f] * rsqrtf(var + EPSn);
    scaleA[f] = a;
    shiftA[f] = be[f] - mean * a;
}

// ---------------- pooling: segmented sums over contiguous batch ranges ----------------

#define PCH 8

__global__ __launch_bounds__(256) void k_pool2(const float* __restrict__ h,
                                               const int* __restrict__ gstart,
                                               const float* __restrict__ scaleA,
                                               const float* __restrict__ shiftA,
                                               float* __restrict__ pooled) {
    int g = blockIdx.x;
    int chunk = blockIdx.y;
    int f = threadIdx.x;
    int s = gstart[g], e = gstart[g + 1];
    int len = e - s;
    if (len <= 0) return;
    int per = (len + PCH - 1) / PCH;
    int cs = s + chunk * per;
    int ce = cs + per; if (ce > e) ce = e;
    if (cs >= ce) return;
    float sc = scaleA[f], sh = shiftA[f];
    float acc = 0.0f;
    for (int i = cs; i < ce; i++)
        acc += h[(size_t)i * Hn + f] * sc + sh;
    atomicAdd(&pooled[g * Hn + f], acc);
}

// ---------------- head ----------------

__global__ __launch_bounds__(256) void k_head1init(const float* __restrict__ pooled,
                                                   const int* __restrict__ gstart,
                                                   const float* __restrict__ fc1_b,
                                                   float* __restrict__ pfinal) {
    int gidx = blockIdx.x;
    int j = threadIdx.x;
    float cntf = (float)(gstart[gidx + 1] - gstart[gidx]);
    cntf = fmaxf(cntf, 1.0f);
    pfinal[gidx * Hn + j] = pooled[gidx * Hn + j] / cntf + fc1_b[j];
}

__global__ __launch_bounds__(256) void k_head1part(const float* __restrict__ seq_emb,
                                                   const float* __restrict__ fc1_w,
                                                   float* __restrict__ pfinal) {
    int gidx = blockIdx.x;   // 16
    int kc = blockIdx.y;     // 10 chunks of 128
    int j = threadIdx.x;     // 256
    const float* se = &seq_emb[(size_t)gidx * DINn + kc * 128];
    const float* w = &fc1_w[(size_t)kc * 128 * Hn + j];
    float acc = 0.0f;
    #pragma unroll 8
    for (int k = 0; k < 128; k++)
        acc += se[k] * w[(size_t)k * Hn];
    atomicAdd(&pfinal[gidx * Hn + j], acc);
}

__global__ __launch_bounds__(512) void k_head2(const float* __restrict__ pfinal,
                                               const float* __restrict__ lin_w,
                                               const float* __restrict__ lin_b,
                                               float* __restrict__ out) {
    int gidx = blockIdx.x;
    int c = threadIdx.x;
    if (c >= Cn) return;
    float acc = lin_b[c];
    const float* p = &pfinal[gidx * Hn];
    #pragma unroll 8
    for (int k = 0; k < Hn; k++)
        acc += p[k] * lin_w[(size_t)k * Cn + c];
    out[gidx * Cn + c] = 1.0f / (1.0f + expf(-acc));
}

// ---------------- launch ----------------

extern "C" void kernel_launch(void* const* d_in, const int* in_sizes, int n_in,
                              void* d_out, int out_size, void* d_ws, size_t ws_size,
                              hipStream_t stream) {
    const float* x        = (const float*)d_in[0];
    const int*   eidx     = (const int*)d_in[1];
    const float* eattr    = (const float*)d_in[2];
    const int*   batch    = (const int*)d_in[3];
    const float* seq_emb  = (const float*)d_in[4];
    const float* W1 = (const float*)d_in[5];
    const float* b1 = (const float*)d_in[6];
    const float* g1 = (const float*)d_in[7];
    const float* be1 = (const float*)d_in[8];
    const float* W2 = (const float*)d_in[9];
    const float* b2 = (const float*)d_in[10];
    const float* g2 = (const float*)d_in[11];
    const float* be2 = (const float*)d_in[12];
    const float* W3 = (const float*)d_in[13];
    const float* b3 = (const float*)d_in[14];
    const float* g3 = (const float*)d_in[15];
    const float* be3 = (const float*)d_in[16];
    const float* fc1_w = (const float*)d_in[17];
    const float* fc1_b = (const float*)d_in[18];
    const float* lin_w = (const float*)d_in[19];
    const float* lin_b = (const float*)d_in[20];
    float* out = (float*)d_out;

    const int* row = eidx;
    const int* col = eidx + En;

    char* ws = (char*)d_ws;
    size_t off = 0;
    auto alloc = [&](size_t bytes) -> char* {
        char* p = ws + off;
        off += (bytes + 255) & ~(size_t)255;
        return p;
    };
    float* xw      = (float*)alloc((size_t)Nn * Hn * 4);
    float* hbuf    = (float*)alloc((size_t)Nn * Hn * 4);
    float* deg     = (float*)alloc(Nn * 4);
    int*   counts  = (int*)alloc(Nn * 4);
    float* dinv    = (float*)alloc(Nn * 4);
    float* dinv2   = (float*)alloc(Nn * 4);
    float* normE   = (float*)alloc(En * 4);
    int*   offsets = (int*)alloc((Nn + 1) * 4);
    int*   cursor  = (int*)alloc(Nn * 4);
    int*   csr_row = (int*)alloc(En * 4);
    float* csr_w   = (float*)alloc(En * 4);
    float* stats   = (float*)alloc(2 * Hn * 4);
    float* scaleA  = (float*)alloc(Hn * 4);
    float* shiftA  = (float*)alloc(Hn * 4);
    float* pooled  = (float*)alloc(Gn * Hn * 4);
    int*   gstart  = (int*)alloc((Gn + 1) * 4);
    float* pfinal  = (float*)alloc(Gn * Hn * 4);
    float* partial = (float*)alloc((size_t)BNB * 512 * 4);
    ushort* W1T    = (ushort*)alloc((size_t)Hn * DINn * 2);
    ushort* W2T    = (ushort*)alloc((size_t)Hn * Hn * 2);
    ushort* W3T    = (ushort*)alloc((size_t)Hn * Hn * 2);

    const int TB = 256;
    const int EB = (En + TB - 1) / TB;
    const int NB = (Nn + TB - 1) / TB;

    // ---- graph prep + weight prep ----
    hipMemsetAsync(deg, 0, Nn * 4, stream);
    hipMemsetAsync(counts, 0, Nn * 4, stream);
    k_deg<<<EB, TB, 0, stream>>>(col, eattr, deg);
    k_dinv<<<NB, TB, 0, stream>>>(deg, dinv, dinv2);
    k_norm_count<<<EB, TB, 0, stream>>>(row, col, eattr, dinv, normE, counts);
    k_scan<<<1, 1024, 0, stream>>>(counts, offsets, cursor);
    k_fill<<<EB, TB, 0, stream>>>(row, col, normE, cursor, csr_row, csr_w);
    k_gbounds<<<NB, TB, 0, stream>>>(batch, gstart);
    k_wt<<<dim3(DINn / 32, Hn / 32), dim3(32, 8), 0, stream>>>(W1, W1T, DINn);
    k_wt<<<dim3(Hn / 32, Hn / 32), dim3(32, 8), 0, stream>>>(W2, W2T, Hn);
    k_wt<<<dim3(Hn / 32, Hn / 32), dim3(32, 8), 0, stream>>>(W3, W3T, Hn);

    dim3 gg((Nn + GBM - 1) / GBM, Hn / GBN);
    const int AGB = Nn / 4;   // k_agg blocks (4 nodes per block)

    // ---- layer 1 ----
    k_gemm_mfma<<<gg, 256, 0, stream>>>(x, W1T, xw, Nn, DINn, nullptr, nullptr);
    k_agg<<<AGB, 256, 0, stream>>>(xw, offsets, csr_row, csr_w, dinv2, b1, hbuf, 1);
    hipMemsetAsync(stats, 0, 2 * Hn * 4, stream);
    k_bnpart<<<BNB, Hn, 0, stream>>>(hbuf, partial);
    k_bnred<<<BNB / 64, Hn, 0, stream>>>(partial, stats);
    k_bnfinal<<<1, Hn, 0, stream>>>(stats, g1, be1, scaleA, shiftA);

    // ---- layer 2 ----
    k_gemm_mfma<<<gg, 256, 0, stream>>>(hbuf, W2T, xw, Nn, Hn, scaleA, shiftA);
    k_agg<<<AGB, 256, 0, stream>>>(xw, offsets, csr_row, csr_w, dinv2, b2, hbuf, 1);
    hipMemsetAsync(stats, 0, 2 * Hn * 4, stream);
    k_bnpart<<<BNB, Hn, 0, stream>>>(hbuf, partial);
    k_bnred<<<BNB / 64, Hn, 0, stream>>>(partial, stats);
    k_bnfinal<<<1, Hn, 0, stream>>>(stats, g2, be2, scaleA, shiftA);

    // ---- layer 3 ----
    k_gemm_mfma<<<gg, 256, 0, stream>>>(hbuf, W3T, xw, Nn, Hn, scaleA, shiftA);
    k_agg<<<AGB, 256, 0, stream>>>(xw, offsets, csr_row, csr_w, dinv2, b3, hbuf, 0);
    hipMemsetAsync(stats, 0, 2 * Hn * 4, stream);
    k_bnpart<<<BNB, Hn, 0, stream>>>(hbuf, partial);
    k_bnred<<<BNB / 64, Hn, 0, stream>>>(partial, stats);
    k_bnfinal<<<1, Hn, 0, stream>>>(stats, g3, be3, scaleA, shiftA);

    // ---- pooling ----
    hipMemsetAsync(pooled, 0, Gn * Hn * 4, stream);
    k_pool2<<<dim3(Gn, PCH), Hn, 0, stream>>>(hbuf, gstart, scaleA, shiftA, pooled);

    // ---- head ----
    k_head1init<<<Gn, Hn, 0, stream>>>(pooled, gstart, fc1_b, pfinal);
    k_head1part<<<dim3(Gn, DINn / 128), Hn, 0, stream>>>(seq_emb, fc1_w, pfinal);
    k_head2<<<Gn, 512, 0, stream>>>(pfinal, lin_w, lin_b, out);
}

// Round 6
// 426.302 us; speedup vs baseline: 2.7352x; 1.0555x over previous
//
#include <hip/hip_runtime.h>
#include <hip/hip_bf16.h>
#include <math.h>

#define Nn 20000
#define En 320000
#define Gn 16
#define DINn 1280
#define Hn 256
#define Cn 500
#define EPSn 1e-5f
#define BNB 1024

typedef __attribute__((ext_vector_type(8))) short bf16x8;
typedef __attribute__((ext_vector_type(4))) float f32x4;

__device__ __forceinline__ float b2f(ushort u) {
    return __uint_as_float(((unsigned int)u) << 16);
}
__device__ __forceinline__ ushort f2b(float f) {
    __hip_bfloat16 h = __float2bfloat16(f);
    return *reinterpret_cast<ushort*>(&h);
}

#define GLOAD16(g, l) __builtin_amdgcn_global_load_lds( \
    (const __attribute__((address_space(1))) unsigned int*)(g), \
    (__attribute__((address_space(3))) unsigned int*)(l), 16, 0, 0)

// ---------------- degree / norm / CSR build ----------------

__global__ void k_deg(const int* col, const float* ew, float* deg) {
    int e = blockIdx.x * blockDim.x + threadIdx.x;
    if (e < En) atomicAdd(&deg[col[e]], ew[e]);
}

__global__ void k_dinv(const float* deg, float* dinv, float* dinv2) {
    int i = blockIdx.x * blockDim.x + threadIdx.x;
    if (i < Nn) {
        float d = deg[i] + 1.0f;
        float r = rsqrtf(d);
        dinv[i] = r;
        dinv2[i] = 1.0f / d;
    }
}

__global__ void k_norm_count(const int* row, const int* col, const float* ew,
                             const float* dinv, float* normE, int* counts) {
    int e = blockIdx.x * blockDim.x + threadIdx.x;
    if (e < En) {
        int r = row[e], c = col[e];
        normE[e] = dinv[r] * ew[e] * dinv[c];
        atomicAdd(&counts[c], 1);
    }
}

__global__ void k_scan(const int* counts, int* offsets, int* cursor) {
    __shared__ int sdata[1024];
    __shared__ int s_running;
    int tid = threadIdx.x;
    if (tid == 0) s_running = 0;
    __syncthreads();
    for (int base = 0; base < Nn; base += 1024) {
        int i = base + tid;
        int v = (i < Nn) ? counts[i] : 0;
        sdata[tid] = v;
        __syncthreads();
        #pragma unroll
        for (int offi = 1; offi < 1024; offi <<= 1) {
            int t = (tid >= offi) ? sdata[tid - offi] : 0;
            __syncthreads();
            sdata[tid] += t;
            __syncthreads();
        }
        int incl = sdata[tid];
        int excl = incl - v;
        if (i < Nn) {
            int o = s_running + excl;
            offsets[i] = o;
            cursor[i] = o;
        }
        __syncthreads();
        if (tid == 1023) s_running += sdata[1023];
        __syncthreads();
    }
    if (tid == 0) offsets[Nn] = s_running;
}

__global__ void k_fill(const int* row, const int* col, const float* normE,
                       int* cursor, int* csr_row, float* csr_w) {
    int e = blockIdx.x * blockDim.x + threadIdx.x;
    if (e < En) {
        int c = col[e];
        int p = atomicAdd(&cursor[c], 1);
        csr_row[p] = row[e];
        csr_w[p] = normE[e];
    }
}

// ---------------- group bounds from sorted batch ----------------

__global__ void k_gbounds(const int* __restrict__ batch, int* __restrict__ gstart) {
    int i = blockIdx.x * blockDim.x + threadIdx.x;
    if (i >= Nn) return;
    int b = batch[i];
    if (i == 0) {
        for (int g = 0; g <= b; g++) gstart[g] = 0;
    } else {
        int pb = batch[i - 1];
        for (int g = pb + 1; g <= b; g++) gstart[g] = i;
    }
    if (i == Nn - 1) {
        for (int g = b + 1; g <= Gn; g++) gstart[g] = Nn;
    }
}

// ---------------- x -> bf16 ----------------

__global__ __launch_bounds__(256) void k_x2bf(const float* __restrict__ x,
                                              ushort* __restrict__ xb) {
    size_t i = ((size_t)blockIdx.x * blockDim.x + threadIdx.x) * 8;
    const float4* xp = reinterpret_cast<const float4*>(&x[i]);
    float4 a = xp[0], b = xp[1];
    ushort t[8];
    t[0] = f2b(a.x); t[1] = f2b(a.y); t[2] = f2b(a.z); t[3] = f2b(a.w);
    t[4] = f2b(b.x); t[5] = f2b(b.y); t[6] = f2b(b.z); t[7] = f2b(b.w);
    *reinterpret_cast<uint4*>(&xb[i]) = *reinterpret_cast<uint4*>(&t[0]);
}

// ---------------- plain weight transpose (W1): WT[n][k] = bf16(W[k][n]) ----------------

__global__ __launch_bounds__(256) void k_wt(const float* __restrict__ W,
                                            ushort* __restrict__ WT, int K) {
    __shared__ float tile[32][33];
    int k0 = blockIdx.x * 32, n0 = blockIdx.y * 32;
    int tx = threadIdx.x, ty = threadIdx.y;   // (32, 8)
    #pragma unroll
    for (int i = 0; i < 32; i += 8)
        tile[ty + i][tx] = W[(size_t)(k0 + ty + i) * Hn + n0 + tx];
    __syncthreads();
    #pragma unroll
    for (int i = 0; i < 32; i += 8)
        WT[(size_t)(n0 + ty + i) * K + k0 + tx] = f2b(tile[tx][ty + i]);
}

// ---------------- affine-folded weight transform (W2/W3, K=256) ----------------
// WT[n][k] = bf16(scaleA[k]*W[k][n]);  bv[n] += sum_k shiftA[k]*W[k][n]

__global__ __launch_bounds__(256) void k_wtb(const float* __restrict__ W,
                                             const float* __restrict__ scaleA,
                                             const float* __restrict__ shiftA,
                                             ushort* __restrict__ WT,
                                             float* __restrict__ bv) {
    __shared__ float tile[32][33];
    int k0 = blockIdx.x * 32, n0 = blockIdx.y * 32;
    int tx = threadIdx.x, ty = threadIdx.y;   // (32, 8)
    #pragma unroll
    for (int i = 0; i < 32; i += 8)
        tile[ty + i][tx] = W[(size_t)(k0 + ty + i) * Hn + n0 + tx];
    __syncthreads();
    float sc = scaleA[k0 + tx], sh = shiftA[k0 + tx];
    #pragma unroll
    for (int i = 0; i < 32; i += 8) {
        float w = tile[tx][ty + i];   // k = k0+tx, n = n0+ty+i
        WT[(size_t)(n0 + ty + i) * Hn + k0 + tx] = f2b(w * sc);
        float pb = w * sh;
        #pragma unroll
        for (int o = 16; o > 0; o >>= 1) pb += __shfl_down(pb, o, 32);
        if (tx == 0) atomicAdd(&bv[n0 + ty + i], pb);
    }
}

// ---------------- bf16 MFMA GEMM: C[M x 256] = A @ WT^T ----------------
// A: M x K bf16 row-major; BT: 256 x K bf16; C bf16.
// Tiles staged with global_load_lds (linear LDS dest) + XOR-swizzled source,
// ds_read applies the same XOR (rule #21 both-sides pattern).

#define GBM 64
#define GBN 128
#define GBK 64

__global__ __launch_bounds__(256) void k_gemm_bf(
    const ushort* __restrict__ A, const ushort* __restrict__ BT,
    ushort* __restrict__ C, int M, int K)
{
    __shared__ ushort Asl[GBM][GBK];   // 8 KB
    __shared__ ushort Bsl[GBN][GBK];   // 16 KB
    const int bm = blockIdx.x * GBM;
    const int bn = blockIdx.y * GBN;
    const int tid = threadIdx.x;
    const int lane = tid & 63;
    const int wid = tid >> 6;
    const int wm = wid >> 1, wn = wid & 1;   // wave tile 32(M) x 64(N)
    const int l15 = lane & 15, l16 = lane >> 4;

    // staging: each gload moves 1KB = 8 rows of 128B; lane -> (row=lane>>3, col=(lane&7)*16)
    // source col pre-swizzled so LDS[row][c] = A[row][c ^ ((row&7)<<4)]
    const int lrow = lane >> 3;
    const int lcolb = 16 * ((lane & 7) ^ lrow);

    f32x4 acc[2][4] = {};
    const int nt = K / GBK;

    for (int t = 0; t < nt; t++) {
        const int k0 = t * GBK;
        #pragma unroll
        for (int c = 0; c < 2; c++) {
            int chunk = wid * 2 + c;          // 8 chunks over A
            int grow = bm + chunk * 8 + lrow;
            if (grow >= M) grow = M - 1;
            const char* src = (const char*)&A[(size_t)grow * K + k0] + lcolb;
            GLOAD16(src, &Asl[chunk * 8][0]);
        }
        #pragma unroll
        for (int c = 0; c < 4; c++) {
            int chunk = wid * 4 + c;          // 16 chunks over B
            int grow = bn + chunk * 8 + lrow;
            const char* src = (const char*)&BT[(size_t)grow * K + k0] + lcolb;
            GLOAD16(src, &Bsl[chunk * 8][0]);
        }
        __syncthreads();

        #pragma unroll
        for (int ks = 0; ks < 2; ks++) {
            bf16x8 afr[2], bfr[4];
            #pragma unroll
            for (int i = 0; i < 2; i++) {
                int r = wm * 32 + i * 16 + l15;
                int cb = (ks * 64 + l16 * 16) ^ ((r & 7) << 4);
                afr[i] = *reinterpret_cast<const bf16x8*>((const char*)&Asl[r][0] + cb);
            }
            #pragma unroll
            for (int j = 0; j < 4; j++) {
                int r = wn * 64 + j * 16 + l15;
                int cb = (ks * 64 + l16 * 16) ^ ((r & 7) << 4);
                bfr[j] = *reinterpret_cast<const bf16x8*>((const char*)&Bsl[r][0] + cb);
            }
            #pragma unroll
            for (int i = 0; i < 2; i++)
                #pragma unroll
                for (int j = 0; j < 4; j++)
                    acc[i][j] = __builtin_amdgcn_mfma_f32_16x16x32_bf16(afr[i], bfr[j], acc[i][j], 0, 0, 0);
        }
        __syncthreads();
    }

    #pragma unroll
    for (int i = 0; i < 2; i++) {
        #pragma unroll
        for (int r = 0; r < 4; r++) {
            int grow = bm + wm * 32 + i * 16 + l16 * 4 + r;
            if (grow < M) {
                #pragma unroll
                for (int j = 0; j < 4; j++)
                    C[(size_t)grow * Hn + bn + wn * 64 + j * 16 + l15] = f2b(acc[i][j][r]);
            }
        }
    }
}

// ---------------- aggregation: one wave per node, bf16 in/out ----------------
// out[i][n] = sum_e w_e*xw[r_e][n] + dinv2*xw[i][n] + (sum_e w_e + dinv2)*bv[n] + b[n]

__global__ __launch_bounds__(256) void k_agg(const ushort* __restrict__ xw,
                                             const int* __restrict__ offsets,
                                             const int* __restrict__ csr_row,
                                             const float* __restrict__ csr_w,
                                             const float* __restrict__ dinv2,
                                             const float* __restrict__ bias,
                                             const float* __restrict__ bv,
                                             ushort* __restrict__ outp, int do_relu) {
    int node = blockIdx.x * 4 + (threadIdx.x >> 6);
    int lane = threadIdx.x & 63;
    int s = offsets[node], e = offsets[node + 1];
    const ushort4* xw4 = reinterpret_cast<const ushort4*>(xw);  // row = 64 ushort4
    float a0 = 0.f, a1 = 0.f, a2 = 0.f, a3 = 0.f;
    float wsum = 0.f;
    for (int k = s; k < e; k++) {
        int r = csr_row[k];
        float w = csr_w[k];
        wsum += w;
        ushort4 v = xw4[(size_t)r * 64 + lane];
        a0 += w * b2f(v.x); a1 += w * b2f(v.y);
        a2 += w * b2f(v.z); a3 += w * b2f(v.w);
    }
    float d2 = dinv2[node];
    wsum += d2;
    ushort4 v = xw4[(size_t)node * 64 + lane];
    a0 += d2 * b2f(v.x); a1 += d2 * b2f(v.y);
    a2 += d2 * b2f(v.z); a3 += d2 * b2f(v.w);
    float4 bb = reinterpret_cast<const float4*>(bias)[lane];
    a0 += bb.x; a1 += bb.y; a2 += bb.z; a3 += bb.w;
    if (bv) {
        float4 bvv = reinterpret_cast<const float4*>(bv)[lane];
        a0 += wsum * bvv.x; a1 += wsum * bvv.y;
        a2 += wsum * bvv.z; a3 += wsum * bvv.w;
    }
    if (do_relu) {
        a0 = fmaxf(a0, 0.f); a1 = fmaxf(a1, 0.f);
        a2 = fmaxf(a2, 0.f); a3 = fmaxf(a3, 0.f);
    }
    ushort4 o;
    o.x = f2b(a0); o.y = f2b(a1); o.z = f2b(a2); o.w = f2b(a3);
    reinterpret_cast<ushort4*>(outp)[(size_t)node * 64 + lane] = o;
}

// ---------------- batch-norm stats ----------------

__global__ __launch_bounds__(256) void k_bnpart(const ushort* __restrict__ h,
                                                float* __restrict__ partial) {
    int f = threadIdx.x;
    int blk = blockIdx.x;
    float s = 0.0f, ss = 0.0f;
    for (int i = blk; i < Nn; i += BNB) {
        float v = b2f(h[(size_t)i * Hn + f]);
        s += v;
        ss += v * v;
    }
    partial[(size_t)blk * 512 + f] = s;
    partial[(size_t)blk * 512 + 256 + f] = ss;
}

__global__ __launch_bounds__(256) void k_bnred(const float* __restrict__ partial,
                                               float* __restrict__ stats) {
    int f = threadIdx.x;
    int b0 = blockIdx.x * 64;
    float s = 0.0f, ss = 0.0f;
    for (int j = 0; j < 64; j++) {
        const float* p = &partial[(size_t)(b0 + j) * 512];
        s += p[f];
        ss += p[256 + f];
    }
    atomicAdd(&stats[f], s);
    atomicAdd(&stats[Hn + f], ss);
}

__global__ void k_bnfinal(const float* stats, const float* g, const float* be,
                          float* scaleA, float* shiftA) {
    int f = threadIdx.x;
    float mean = stats[f] / (float)Nn;
    float var = stats[Hn + f] / (float)Nn - mean * mean;
    float a = g[f] * rsqrtf(var + EPSn);
    scaleA[f] = a;
    shiftA[f] = be[f] - mean * a;
}

// ---------------- pooling ----------------

#define PCH 8

__global__ __launch_bounds__(256) void k_pool2(const ushort* __restrict__ h,
                                               const int* __restrict__ gstart,
                                               const float* __restrict__ scaleA,
                                               const float* __restrict__ shiftA,
                                               float* __restrict__ pooled) {
    int g = blockIdx.x;
    int chunk = blockIdx.y;
    int f = threadIdx.x;
    int s = gstart[g], e = gstart[g + 1];
    int len = e - s;
    if (len <= 0) return;
    int per = (len + PCH - 1) / PCH;
    int cs = s + chunk * per;
    int ce = cs + per; if (ce > e) ce = e;
    if (cs >= ce) return;
    float sc = scaleA[f], sh = shiftA[f];
    float acc = 0.0f;
    for (int i = cs; i < ce; i++)
        acc += b2f(h[(size_t)i * Hn + f]) * sc + sh;
    atomicAdd(&pooled[g * Hn + f], acc);
}

// ---------------- head ----------------

__global__ __launch_bounds__(256) void k_head1init(const float* __restrict__ pooled,
                                                   const int* __restrict__ gstart,
                                                   const float* __restrict__ fc1_b,
                                                   float* __restrict__ pfinal) {
    int gidx = blockIdx.x;
    int j = threadIdx.x;
    float cntf = (float)(gstart[gidx + 1] - gstart[gidx]);
    cntf = fmaxf(cntf, 1.0f);
    pfinal[gidx * Hn + j] = pooled[gidx * Hn + j] / cntf + fc1_b[j];
}

__global__ __launch_bounds__(256) void k_head1part(const float* __restrict__ seq_emb,
                                                   const float* __restrict__ fc1_w,
                                                   float* __restrict__ pfinal) {
    int gidx = blockIdx.x;
    int kc = blockIdx.y;
    int j = threadIdx.x;
    const float* se = &seq_emb[(size_t)gidx * DINn + kc * 128];
    const float* w = &fc1_w[(size_t)kc * 128 * Hn + j];
    float acc = 0.0f;
    #pragma unroll 8
    for (int k = 0; k < 128; k++)
        acc += se[k] * w[(size_t)k * Hn];
    atomicAdd(&pfinal[gidx * Hn + j], acc);
}

__global__ __launch_bounds__(512) void k_head2(const float* __restrict__ pfinal,
                                               const float* __restrict__ lin_w,
                                               const float* __restrict__ lin_b,
                                               float* __restrict__ out) {
    int gidx = blockIdx.x;
    int c = threadIdx.x;
    if (c >= Cn) return;
    float acc = lin_b[c];
    const float* p = &pfinal[gidx * Hn];
    #pragma unroll 8
    for (int k = 0; k < Hn; k++)
        acc += p[k] * lin_w[(size_t)k * Cn + c];
    out[gidx * Cn + c] = 1.0f / (1.0f + expf(-acc));
}

// ---------------- launch ----------------

extern "C" void kernel_launch(void* const* d_in, const int* in_sizes, int n_in,
                              void* d_out, int out_size, void* d_ws, size_t ws_size,
                              hipStream_t stream) {
    const float* x        = (const float*)d_in[0];
    const int*   eidx     = (const int*)d_in[1];
    const float* eattr    = (const float*)d_in[2];
    const int*   batch    = (const int*)d_in[3];
    const float* seq_emb  = (const float*)d_in[4];
    const float* W1 = (const float*)d_in[5];
    const float* b1 = (const float*)d_in[6];
    const float* g1 = (const float*)d_in[7];
    const float* be1 = (const float*)d_in[8];
    const float* W2 = (const float*)d_in[9];
    const float* b2 = (const float*)d_in[10];
    const float* g2 = (const float*)d_in[11];
    const float* be2 = (const float*)d_in[12];
    const float* W3 = (const float*)d_in[13];
    const float* b3 = (const float*)d_in[14];
    const float* g3 = (const float*)d_in[15];
    const float* be3 = (const float*)d_in[16];
    const float* fc1_w = (const float*)d_in[17];
    const float* fc1_b = (const float*)d_in[18];
    const float* lin_w = (const float*)d_in[19];
    const float* lin_b = (const float*)d_in[20];
    float* out = (float*)d_out;

    const int* row = eidx;
    const int* col = eidx + En;

    char* ws = (char*)d_ws;
    size_t off = 0;
    auto alloc = [&](size_t bytes) -> char* {
        char* p = ws + off;
        off += (bytes + 255) & ~(size_t)255;
        return p;
    };
    ushort* xb     = (ushort*)alloc((size_t)Nn * DINn * 2);
    ushort* xwb    = (ushort*)alloc((size_t)Nn * Hn * 2);
    ushort* hb     = (ushort*)alloc((size_t)Nn * Hn * 2);
    float* deg     = (float*)alloc(Nn * 4);
    int*   counts  = (int*)alloc(Nn * 4);
    float* dinv    = (float*)alloc(Nn * 4);
    float* dinv2   = (float*)alloc(Nn * 4);
    float* normE   = (float*)alloc(En * 4);
    int*   offsets = (int*)alloc((Nn + 1) * 4);
    int*   cursor  = (int*)alloc(Nn * 4);
    int*   csr_row = (int*)alloc(En * 4);
    float* csr_w   = (float*)alloc(En * 4);
    float* stats   = (float*)alloc(2 * Hn * 4);
    float* scaleA  = (float*)alloc(Hn * 4);
    float* shiftA  = (float*)alloc(Hn * 4);
    float* pooled  = (float*)alloc(Gn * Hn * 4);
    int*   gstart  = (int*)alloc((Gn + 1) * 4);
    float* pfinal  = (float*)alloc(Gn * Hn * 4);
    float* partial = (float*)alloc((size_t)BNB * 512 * 4);
    float* bv      = (float*)alloc(Hn * 4);
    ushort* W1T    = (ushort*)alloc((size_t)Hn * DINn * 2);
    ushort* W2T    = (ushort*)alloc((size_t)Hn * Hn * 2);
    ushort* W3T    = (ushort*)alloc((size_t)Hn * Hn * 2);

    const int TB = 256;
    const int EB = (En + TB - 1) / TB;
    const int NB = (Nn + TB - 1) / TB;

    // ---- graph prep + input/weight prep ----
    hipMemsetAsync(deg, 0, Nn * 4, stream);
    hipMemsetAsync(counts, 0, Nn * 4, stream);
    k_deg<<<EB, TB, 0, stream>>>(col, eattr, deg);
    k_dinv<<<NB, TB, 0, stream>>>(deg, dinv, dinv2);
    k_norm_count<<<EB, TB, 0, stream>>>(row, col, eattr, dinv, normE, counts);
    k_scan<<<1, 1024, 0, stream>>>(counts, offsets, cursor);
    k_fill<<<EB, TB, 0, stream>>>(row, col, normE, cursor, csr_row, csr_w);
    k_gbounds<<<NB, TB, 0, stream>>>(batch, gstart);
    k_x2bf<<<(Nn * DINn / 8) / 256, 256, 0, stream>>>(x, xb);
    k_wt<<<dim3(DINn / 32, Hn / 32), dim3(32, 8), 0, stream>>>(W1, W1T, DINn);

    dim3 gg((Nn + GBM - 1) / GBM, Hn / GBN);
    const int AGB = Nn / 4;

    // ---- layer 1 ----
    k_gemm_bf<<<gg, 256, 0, stream>>>(xb, W1T, xwb, Nn, DINn);
    k_agg<<<AGB, 256, 0, stream>>>(xwb, offsets, csr_row, csr_w, dinv2, b1, nullptr, hb, 1);
    hipMemsetAsync(stats, 0, 2 * Hn * 4, stream);
    k_bnpart<<<BNB, Hn, 0, stream>>>(hb, partial);
    k_bnred<<<BNB / 64, Hn, 0, stream>>>(partial, stats);
    k_bnfinal<<<1, Hn, 0, stream>>>(stats, g1, be1, scaleA, shiftA);

    // ---- layer 2 (affine folded into W2T', bv) ----
    hipMemsetAsync(bv, 0, Hn * 4, stream);
    k_wtb<<<dim3(Hn / 32, Hn / 32), dim3(32, 8), 0, stream>>>(W2, scaleA, shiftA, W2T, bv);
    k_gemm_bf<<<gg, 256, 0, stream>>>(hb, W2T, xwb, Nn, Hn);
    k_agg<<<AGB, 256, 0, stream>>>(xwb, offsets, csr_row, csr_w, dinv2, b2, bv, hb, 1);
    hipMemsetAsync(stats, 0, 2 * Hn * 4, stream);
    k_bnpart<<<BNB, Hn, 0, stream>>>(hb, partial);
    k_bnred<<<BNB / 64, Hn, 0, stream>>>(partial, stats);
    k_bnfinal<<<1, Hn, 0, stream>>>(stats, g2, be2, scaleA, shiftA);

    // ---- layer 3 ----
    hipMemsetAsync(bv, 0, Hn * 4, stream);
    k_wtb<<<dim3(Hn / 32, Hn / 32), dim3(32, 8), 0, stream>>>(W3, scaleA, shiftA, W3T, bv);
    k_gemm_bf<<<gg, 256, 0, stream>>>(hb, W3T, xwb, Nn, Hn);
    k_agg<<<AGB, 256, 0, stream>>>(xwb, offsets, csr_row, csr_w, dinv2, b3, bv, hb, 0);
    hipMemsetAsync(stats, 0, 2 * Hn * 4, stream);
    k_bnpart<<<BNB, Hn, 0, stream>>>(hb, partial);
    k_bnred<<<BNB / 64, Hn, 0, stream>>>(partial, stats);
    k_bnfinal<<<1, Hn, 0, stream>>>(stats, g3, be3, scaleA, shiftA);

    // ---- pooling ----
    hipMemsetAsync(pooled, 0, Gn * Hn * 4, stream);
    k_pool2<<<dim3(Gn, PCH), Hn, 0, stream>>>(hb, gstart, scaleA, shiftA, pooled);

    // ---- head ----
    k_head1init<<<Gn, Hn, 0, stream>>>(pooled, gstart, fc1_b, pfinal);
    k_head1part<<<dim3(Gn, DINn / 128), Hn, 0, stream>>>(seq_emb, fc1_w, pfinal);
    k_head2<<<Gn, 512, 0, stream>>>(pfinal, lin_w, lin_b, out);
}